// Round 1
// baseline (248.026 us; speedup 1.0000x reference)
//
#include <hip/hip_runtime.h>

typedef __bf16 bf16x8 __attribute__((ext_vector_type(8)));
typedef float  f32x4  __attribute__((ext_vector_type(4)));

#define LOG2E_F 1.44269504088896340736f

static constexpr int kB = 2, kN = 2048, kH = 8, kD = 64, kDim = 512;
static constexpr int kTok = kB * kN;  // 4096

// ================= GEMM: C[M,N] = A[M,K] * B[N,K]^T (NT), fp32 C ===========
// A is fp32 (AF32=true) or bf16 (false); B always fp32 (weights). bf16 MFMA.
// 64x64 tile, BK=32, 4 waves each 32x32 (2x2 frags of 16x16x32).
template<bool AF32>
__global__ __launch_bounds__(256) void gemm_nt(const void* __restrict__ Ap,
                                               const float* __restrict__ Bp,
                                               float* __restrict__ C,
                                               int N, int K) {
  const int tid  = threadIdx.x;
  const int w    = tid >> 6;
  const int lane = tid & 63;
  const int quad = lane >> 4;
  const int lq   = lane & 15;
  const int m0 = blockIdx.y * 64;
  const int n0 = blockIdx.x * 64;
  const int wm = (w >> 1) * 32;
  const int wn = (w & 1) * 32;
  // row stride 40 bf16 = 80B: keeps 16B alignment for b128 ops, <=2-way banks
  __shared__ __bf16 As[64 * 40];
  __shared__ __bf16 Bs[64 * 40];
  const int srow = tid >> 2;
  const int sseg = (tid & 3) << 3;

  const f32x4 zero = {0.f, 0.f, 0.f, 0.f};
  f32x4 acc00 = zero, acc01 = zero, acc10 = zero, acc11 = zero;

  for (int k0 = 0; k0 < K; k0 += 32) {
    if (k0) __syncthreads();
    if constexpr (AF32) {
      const float* p = (const float*)Ap + (size_t)(m0 + srow) * K + k0 + sseg;
      float4 u = *(const float4*)p;
      float4 v = *(const float4*)(p + 4);
      bf16x8 t;
      t[0] = (__bf16)u.x; t[1] = (__bf16)u.y; t[2] = (__bf16)u.z; t[3] = (__bf16)u.w;
      t[4] = (__bf16)v.x; t[5] = (__bf16)v.y; t[6] = (__bf16)v.z; t[7] = (__bf16)v.w;
      *(bf16x8*)&As[srow * 40 + sseg] = t;
    } else {
      *(bf16x8*)&As[srow * 40 + sseg] =
          *(const bf16x8*)((const __bf16*)Ap + (size_t)(m0 + srow) * K + k0 + sseg);
    }
    {
      const float* p = Bp + (size_t)(n0 + srow) * K + k0 + sseg;
      float4 u = *(const float4*)p;
      float4 v = *(const float4*)(p + 4);
      bf16x8 t;
      t[0] = (__bf16)u.x; t[1] = (__bf16)u.y; t[2] = (__bf16)u.z; t[3] = (__bf16)u.w;
      t[4] = (__bf16)v.x; t[5] = (__bf16)v.y; t[6] = (__bf16)v.z; t[7] = (__bf16)v.w;
      *(bf16x8*)&Bs[srow * 40 + sseg] = t;
    }
    __syncthreads();
    // A-frag: A[m=lane&15][k=quad*8+j]; B-frag: B[n=lane&15][k=quad*8+j]
    bf16x8 a0 = *(const bf16x8*)&As[(wm +      lq) * 40 + quad * 8];
    bf16x8 a1 = *(const bf16x8*)&As[(wm + 16 + lq) * 40 + quad * 8];
    bf16x8 b0 = *(const bf16x8*)&Bs[(wn +      lq) * 40 + quad * 8];
    bf16x8 b1 = *(const bf16x8*)&Bs[(wn + 16 + lq) * 40 + quad * 8];
    acc00 = __builtin_amdgcn_mfma_f32_16x16x32_bf16(a0, b0, acc00, 0, 0, 0);
    acc01 = __builtin_amdgcn_mfma_f32_16x16x32_bf16(a0, b1, acc01, 0, 0, 0);
    acc10 = __builtin_amdgcn_mfma_f32_16x16x32_bf16(a1, b0, acc10, 0, 0, 0);
    acc11 = __builtin_amdgcn_mfma_f32_16x16x32_bf16(a1, b1, acc11, 0, 0, 0);
  }
  // C/D layout: col = lane&15, row = quad*4 + reg  [m89/m91 verified]
  const f32x4 av[2][2] = {{acc00, acc01}, {acc10, acc11}};
#pragma unroll
  for (int fm = 0; fm < 2; ++fm)
#pragma unroll
    for (int fn = 0; fn < 2; ++fn)
#pragma unroll
      for (int r = 0; r < 4; ++r)
        C[(size_t)(m0 + wm + fm * 16 + quad * 4 + r) * N + (n0 + wn + fn * 16 + lq)] =
            av[fm][fn][r];
}

// ============== normalize q,k per (token, head) row of 64 ==================
// qn gets SCALE*log2e folded in so attention can use exp2.
__global__ __launch_bounds__(256) void norm_qk(const float* __restrict__ qf,
                                               const float* __restrict__ kvf,
                                               __bf16* __restrict__ qn,
                                               __bf16* __restrict__ kn) {
  const int w    = blockIdx.x * 4 + (threadIdx.x >> 6);
  const int lane = threadIdx.x & 63;
  const int tok = w >> 3, h = w & 7;
  const int b = tok >> 11, n = tok & (kN - 1);
  const size_t dst = (((size_t)(b * kH + h) * kN) + n) * kD + lane;

  float v = qf[(size_t)tok * kDim + h * 64 + lane];
  float ss = v * v;
#pragma unroll
  for (int m = 1; m < 64; m <<= 1) ss += __shfl_xor(ss, m, 64);
  float mag = sqrtf(ss * (1.f / 64)) + 1e-4f;
  qn[dst] = (__bf16)(v / mag * (0.125f * LOG2E_F));

  v = kvf[(size_t)tok * (2 * kDim) + h * 64 + lane];
  ss = v * v;
#pragma unroll
  for (int m = 1; m < 64; m <<= 1) ss += __shfl_xor(ss, m, 64);
  mag = sqrtf(ss * (1.f / 64)) + 1e-4f;
  kn[dst] = (__bf16)(v / mag);
}

// ============== V -> vt[bh][d][n] bf16 (transposed for PV B-frags) =========
__global__ __launch_bounds__(256) void make_vt(const float* __restrict__ kvf,
                                               __bf16* __restrict__ vt) {
  const int bh = blockIdx.y, b = bh >> 3, h = bh & 7;
  const int n0 = blockIdx.x * 64;
  __shared__ __bf16 tile[64][66];
  const int tl = threadIdx.x >> 6;
  const int d  = threadIdx.x & 63;
#pragma unroll
  for (int i = 0; i < 16; ++i) {
    const int n = i * 4 + tl;
    tile[d][n] =
        (__bf16)kvf[((size_t)(b * kN + n0 + n)) * (2 * kDim) + kDim + h * 64 + d];
  }
  __syncthreads();
  const int dr = threadIdx.x >> 2;
  const int c0 = (threadIdx.x & 3) * 16;
  const size_t base = ((size_t)bh * 64 + dr) * kN + n0 + c0;
#pragma unroll
  for (int i = 0; i < 16; ++i) vt[base + i] = tile[dr][c0 + i];
}

// ===================== fused flash attention per (bh, qtile) ===============
// block = 64 q rows, 4 waves x 16 rows. K/V frags straight from global.
// P goes through per-wave LDS in A-frag order (conflict-free re-read).
__global__ __launch_bounds__(256) void attn_fused(const __bf16* __restrict__ qn,
                                                  const __bf16* __restrict__ kn,
                                                  const __bf16* __restrict__ vt,
                                                  __bf16* __restrict__ ao) {
  const int bh = blockIdx.y;
  const int qt = blockIdx.x;
  const int tid = threadIdx.x;
  const int w = tid >> 6, lane = tid & 63, quad = lane >> 4, lq = lane & 15;
  __shared__ __bf16 Ps[4 * 1024];
  __bf16* myP = &Ps[w * 1024];

  const __bf16* Qb = qn + ((size_t)bh * kN + qt * 64 + w * 16 + lq) * kD;
  bf16x8 aq0 = *(const bf16x8*)(Qb + quad * 8);
  bf16x8 aq1 = *(const bf16x8*)(Qb + 32 + quad * 8);

  const f32x4 zero = {0.f, 0.f, 0.f, 0.f};
  f32x4 o[4];
  float mr[4], lr[4];
#pragma unroll
  for (int i = 0; i < 4; ++i) { o[i] = zero; mr[i] = -1e30f; lr[i] = 0.f; }

  const __bf16* Kb = kn + (size_t)bh * kN * kD;
  const __bf16* Vb = vt + (size_t)bh * kD * kN;

  for (int kt = 0; kt < kN / 64; ++kt) {
    // ---- S = Q K^T (scale & log2e already folded into qn) ----
    f32x4 s[4];
#pragma unroll
    for (int fn = 0; fn < 4; ++fn) {
      const __bf16* kp = Kb + ((size_t)kt * 64 + fn * 16 + lq) * kD + quad * 8;
      bf16x8 b0 = *(const bf16x8*)kp;
      bf16x8 b1 = *(const bf16x8*)(kp + 32);
      f32x4 acc = zero;
      acc = __builtin_amdgcn_mfma_f32_16x16x32_bf16(aq0, b0, acc, 0, 0, 0);
      acc = __builtin_amdgcn_mfma_f32_16x16x32_bf16(aq1, b1, acc, 0, 0, 0);
      s[fn] = acc;
    }
    // ---- online softmax; write P into LDS in A-frag order ----
#pragma unroll
    for (int r = 0; r < 4; ++r) {
      float mx = fmaxf(fmaxf(s[0][r], s[1][r]), fmaxf(s[2][r], s[3][r]));
#pragma unroll
      for (int off = 1; off < 16; off <<= 1) mx = fmaxf(mx, __shfl_xor(mx, off, 64));
      const float mnew  = fmaxf(mr[r], mx);
      const float alpha = exp2f(mr[r] - mnew);
      mr[r] = mnew;
      float rs = 0.f;
#pragma unroll
      for (int fn = 0; fn < 4; ++fn) {
        const float pv = exp2f(s[fn][r] - mnew);
        rs += pv;
        const int c = fn * 16 + lq;  // key col
        // elem = (c>>5)*512 + ((c>>3)&3)*128 + row*8 + (c&7)
        myP[((c >> 5) << 9) + (((c >> 3) & 3) << 7) + ((quad * 4 + r) << 3) + (c & 7)] =
            (__bf16)pv;
      }
#pragma unroll
      for (int off = 1; off < 16; off <<= 1) rs += __shfl_xor(rs, off, 64);
      lr[r] = lr[r] * alpha + rs;
      o[0][r] *= alpha; o[1][r] *= alpha; o[2][r] *= alpha; o[3][r] *= alpha;
    }
    // ---- O += P V ----
    bf16x8 ap0 = *(const bf16x8*)(myP + lane * 8);
    bf16x8 ap1 = *(const bf16x8*)(myP + 512 + lane * 8);
#pragma unroll
    for (int fn = 0; fn < 4; ++fn) {
      const __bf16* vp = Vb + ((size_t)fn * 16 + lq) * kN + kt * 64 + quad * 8;
      bf16x8 b0 = *(const bf16x8*)vp;
      bf16x8 b1 = *(const bf16x8*)(vp + 32);
      o[fn] = __builtin_amdgcn_mfma_f32_16x16x32_bf16(ap0, b0, o[fn], 0, 0, 0);
      o[fn] = __builtin_amdgcn_mfma_f32_16x16x32_bf16(ap1, b1, o[fn], 0, 0, 0);
    }
  }
  // ---- epilogue: O/l -> ao[token][h*64+d] (token-major for out-proj) ----
  const int b = bh >> 3, h = bh & 7;
  const int tok0 = b * kN + qt * 64 + w * 16 + quad * 4;
#pragma unroll
  for (int r = 0; r < 4; ++r) {
    const float inv = 1.f / lr[r];
#pragma unroll
    for (int fn = 0; fn < 4; ++fn)
      ao[(size_t)(tok0 + r) * kDim + h * 64 + fn * 16 + lq] = (__bf16)(o[fn][r] * inv);
  }
}

// ===========================================================================
extern "C" void kernel_launch(void* const* d_in, const int* in_sizes, int n_in,
                              void* d_out, int out_size, void* d_ws, size_t ws_size,
                              hipStream_t stream) {
  const float* x    = (const float*)d_in[0];
  const float* Wq   = (const float*)d_in[1];
  const float* Wkv  = (const float*)d_in[2];
  const float* Wout = (const float*)d_in[3];
  float* out = (float*)d_out;
  char* ws = (char*)d_ws;

  float*  q_f  = (float*)(ws);                      //  8 MB  [4096,512] fp32
  float*  kv_f = (float*)(ws + (size_t)(8  << 20)); // 16 MB  [4096,1024] fp32
  __bf16* qn   = (__bf16*)(ws + (size_t)(24 << 20)); // 4 MB  [bh][n][d]
  __bf16* kn   = (__bf16*)(ws + (size_t)(28 << 20)); // 4 MB  [bh][n][d]
  __bf16* vt   = (__bf16*)(ws + (size_t)(32 << 20)); // 4 MB  [bh][d][n]
  __bf16* ao   = (__bf16*)(ws + (size_t)(36 << 20)); // 4 MB  [tok][dim]

  gemm_nt<true><<<dim3(kDim / 64, kTok / 64), 256, 0, stream>>>(x, Wq, q_f, kDim, kDim);
  gemm_nt<true><<<dim3(2 * kDim / 64, kTok / 64), 256, 0, stream>>>(x, Wkv, kv_f,
                                                                    2 * kDim, kDim);
  norm_qk<<<kTok * kH / 4, 256, 0, stream>>>(q_f, kv_f, qn, kn);
  make_vt<<<dim3(kN / 64, kB * kH), 256, 0, stream>>>(kv_f, vt);
  attn_fused<<<dim3(kN / 64, kB * kH), 256, 0, stream>>>(qn, kn, vt, ao);
  gemm_nt<false><<<dim3(kDim / 64, kTok / 64), 256, 0, stream>>>(ao, Wout, out,
                                                                 kDim, kDim);
}

// Round 2
// 224.610 us; speedup vs baseline: 1.1043x; 1.1043x over previous
//
#include <hip/hip_runtime.h>

typedef __bf16 bf16x8 __attribute__((ext_vector_type(8)));
typedef __bf16 bf16x4 __attribute__((ext_vector_type(4)));
typedef float  f32x4  __attribute__((ext_vector_type(4)));

#define LOG2E_F 1.44269504088896340736f

static constexpr int kB = 2, kN = 2048, kH = 8, kD = 64, kDim = 512;
static constexpr int kTok = kB * kN;  // 4096

__device__ __forceinline__ void gld16(const void* g, void* l) {
  __builtin_amdgcn_global_load_lds(
      (const __attribute__((address_space(1))) void*)g,
      (__attribute__((address_space(3))) void*)l, 16, 0, 0);
}

// ============== fp32 -> bf16 converts (x, Wq, Wkv in one; Wout separate) ===
__global__ __launch_bounds__(256) void cvt_main(const float* __restrict__ x,
                                                const float* __restrict__ wq,
                                                const float* __restrict__ wkv,
                                                __bf16* __restrict__ xb,
                                                __bf16* __restrict__ wqb,
                                                __bf16* __restrict__ wkvb) {
  size_t i = ((size_t)blockIdx.x * 256 + threadIdx.x) * 4;
  const float* s;
  __bf16* d;
  size_t off;
  if (i < 2097152)      { s = x;   d = xb;   off = i; }
  else if (i < 2359296) { s = wq;  d = wqb;  off = i - 2097152; }
  else                  { s = wkv; d = wkvb; off = i - 2359296; }
  float4 v = *(const float4*)(s + off);
  bf16x4 t = {(__bf16)v.x, (__bf16)v.y, (__bf16)v.z, (__bf16)v.w};
  *(bf16x4*)(d + off) = t;
}

__global__ __launch_bounds__(256) void cvt_wout(const float* __restrict__ wo,
                                                __bf16* __restrict__ wob) {
  size_t i = ((size_t)blockIdx.x * 256 + threadIdx.x) * 4;
  float4 v = *(const float4*)(wo + i);
  bf16x4 t = {(__bf16)v.x, (__bf16)v.y, (__bf16)v.z, (__bf16)v.w};
  *(bf16x4*)(wob + i) = t;
}

// ======== GEMM: C[M,N] = A[M,K]*B[N,K]^T, all bf16 in, fp32 out ============
// 64x64 tile, BK=64, global_load_lds width-16 staging (m97 pattern).
__global__ __launch_bounds__(256) void gemm_bt(const __bf16* __restrict__ A,
                                               const __bf16* __restrict__ B,
                                               float* __restrict__ C,
                                               int N, int K) {
  const int tid  = threadIdx.x;
  const int w    = tid >> 6;
  const int lane = tid & 63;
  const int quad = lane >> 4;
  const int lq   = lane & 15;
  const int m0 = blockIdx.y * 64;
  const int n0 = blockIdx.x * 64;
  const int wm = (w >> 1) * 32;
  const int wn = (w & 1) * 32;
  __shared__ __bf16 As[4096];  // [64][64], unpadded (global_load_lds layout)
  __shared__ __bf16 Bs[4096];
  const int srow = tid >> 3;
  const int sseg = (tid & 7) * 8;

  const f32x4 zero = {0.f, 0.f, 0.f, 0.f};
  f32x4 acc00 = zero, acc01 = zero, acc10 = zero, acc11 = zero;

  for (int k0 = 0; k0 < K; k0 += 64) {
    if (k0) __syncthreads();
    gld16(A + (size_t)(m0 + srow) * K + k0 + sseg,      &As[tid * 8]);
    gld16(A + (size_t)(m0 + 32 + srow) * K + k0 + sseg, &As[2048 + tid * 8]);
    gld16(B + (size_t)(n0 + srow) * K + k0 + sseg,      &Bs[tid * 8]);
    gld16(B + (size_t)(n0 + 32 + srow) * K + k0 + sseg, &Bs[2048 + tid * 8]);
    __syncthreads();
#pragma unroll
    for (int ks = 0; ks < 2; ++ks) {
      bf16x8 a0 = *(const bf16x8*)&As[(wm +      lq) * 64 + ks * 32 + quad * 8];
      bf16x8 a1 = *(const bf16x8*)&As[(wm + 16 + lq) * 64 + ks * 32 + quad * 8];
      bf16x8 b0 = *(const bf16x8*)&Bs[(wn +      lq) * 64 + ks * 32 + quad * 8];
      bf16x8 b1 = *(const bf16x8*)&Bs[(wn + 16 + lq) * 64 + ks * 32 + quad * 8];
      acc00 = __builtin_amdgcn_mfma_f32_16x16x32_bf16(a0, b0, acc00, 0, 0, 0);
      acc01 = __builtin_amdgcn_mfma_f32_16x16x32_bf16(a0, b1, acc01, 0, 0, 0);
      acc10 = __builtin_amdgcn_mfma_f32_16x16x32_bf16(a1, b0, acc10, 0, 0, 0);
      acc11 = __builtin_amdgcn_mfma_f32_16x16x32_bf16(a1, b1, acc11, 0, 0, 0);
    }
  }
  const f32x4 av[2][2] = {{acc00, acc01}, {acc10, acc11}};
#pragma unroll
  for (int fm = 0; fm < 2; ++fm)
#pragma unroll
    for (int fn = 0; fn < 2; ++fn)
#pragma unroll
      for (int r = 0; r < 4; ++r)
        C[(size_t)(m0 + wm + fm * 16 + quad * 4 + r) * N + (n0 + wn + fn * 16 + lq)] =
            av[fm][fn][r];
}

// ============== normalize q,k per (token, head) row of 64 ==================
__global__ __launch_bounds__(256) void norm_qk(const float* __restrict__ qf,
                                               const float* __restrict__ kvf,
                                               __bf16* __restrict__ qn,
                                               __bf16* __restrict__ kn) {
  const int w    = blockIdx.x * 4 + (threadIdx.x >> 6);
  const int lane = threadIdx.x & 63;
  const int tok = w >> 3, h = w & 7;
  const int b = tok >> 11, n = tok & (kN - 1);
  const size_t dst = (((size_t)(b * kH + h) * kN) + n) * kD + lane;

  float v = qf[(size_t)tok * kDim + h * 64 + lane];
  float ss = v * v;
#pragma unroll
  for (int m = 1; m < 64; m <<= 1) ss += __shfl_xor(ss, m, 64);
  float mag = sqrtf(ss * (1.f / 64)) + 1e-4f;
  qn[dst] = (__bf16)(v / mag * (0.125f * LOG2E_F));  // fold SCALE*log2e

  v = kvf[(size_t)tok * (2 * kDim) + h * 64 + lane];
  ss = v * v;
#pragma unroll
  for (int m = 1; m < 64; m <<= 1) ss += __shfl_xor(ss, m, 64);
  mag = sqrtf(ss * (1.f / 64)) + 1e-4f;
  kn[dst] = (__bf16)(v / mag);
}

// ====== V -> vt[bh][d][key-permuted n] bf16; pos k' holds key pi(k') =======
// pi(k') = (k'&3)*16 + (k'>>2): matches P A-frag LDS layout in attn.
__global__ __launch_bounds__(256) void make_vt(const float* __restrict__ kvf,
                                               __bf16* __restrict__ vt) {
  const int bh = blockIdx.y, b = bh >> 3, h = bh & 7;
  const int n0 = blockIdx.x * 64;
  __shared__ __bf16 tile[64][66];
  const int tl = threadIdx.x >> 6;
  const int d  = threadIdx.x & 63;
#pragma unroll
  for (int i = 0; i < 16; ++i) {
    const int n = i * 4 + tl;
    tile[d][n] =
        (__bf16)kvf[((size_t)(b * kN + n0 + n)) * (2 * kDim) + kDim + h * 64 + d];
  }
  __syncthreads();
  const int dr = threadIdx.x >> 2;
  const int c0 = (threadIdx.x & 3) * 16;
  const size_t base = ((size_t)bh * 64 + dr) * kN + n0 + c0;
#pragma unroll
  for (int i = 0; i < 16; ++i) {
    const int kp = c0 + i;
    vt[base + i] = tile[dr][((kp & 3) << 4) + (kp >> 2)];
  }
}

// ===================== fused attention per (bh, qtile) =====================
// Fixed-max softmax: scores bounded by 8*SCALE*log2e = 11.54 < 12, so
// p = exp2(s - 12) with -12 folded into MFMA C-init. No max tracking, no
// rescaling, no per-tile shuffles; l reduced once at the end.
__global__ __launch_bounds__(256) void attn_fused(const __bf16* __restrict__ qn,
                                                  const __bf16* __restrict__ kn,
                                                  const __bf16* __restrict__ vt,
                                                  __bf16* __restrict__ ao) {
  const int bh = blockIdx.y;
  const int qt = blockIdx.x;
  const int tid = threadIdx.x;
  const int w = tid >> 6, lane = tid & 63, quad = lane >> 4, lq = lane & 15;
  // P tile per wave: 16 rows x 64 keys, row stride 72 (bank-min for b64
  // writes and b128 reads), double-buffered on kt parity.
  __shared__ __bf16 Ps[4 * 2 * 1152];
  __bf16* Pbase = &Ps[w * 2 * 1152];

  const __bf16* Qb = qn + ((size_t)bh * kN + qt * 64 + w * 16 + lq) * kD;
  bf16x8 aq0 = *(const bf16x8*)(Qb + quad * 8);
  bf16x8 aq1 = *(const bf16x8*)(Qb + 32 + quad * 8);

  const f32x4 zero   = {0.f, 0.f, 0.f, 0.f};
  const f32x4 minit  = {-12.f, -12.f, -12.f, -12.f};
  f32x4 o[4];
  float lr[4];
#pragma unroll
  for (int i = 0; i < 4; ++i) { o[i] = zero; lr[i] = 0.f; }

  const __bf16* Kb = kn + (size_t)bh * kN * kD;
  const __bf16* Vb = vt + (size_t)bh * kD * kN;

#pragma unroll 2
  for (int kt = 0; kt < kN / 64; ++kt) {
    __bf16* myP = Pbase + (kt & 1) * 1152;
    // ---- V loads up front (latency hidden by S + exp section) ----
    bf16x8 vb0[4], vb1[4];
#pragma unroll
    for (int fn = 0; fn < 4; ++fn) {
      const __bf16* vp = Vb + ((size_t)fn * 16 + lq) * kN + kt * 64 + quad * 8;
      vb0[fn] = *(const bf16x8*)vp;
      vb1[fn] = *(const bf16x8*)(vp + 32);
    }
    // ---- S = Q K^T - 12 (bias folded into acc init) ----
    f32x4 s[4];
#pragma unroll
    for (int fn = 0; fn < 4; ++fn) {
      const __bf16* kp = Kb + ((size_t)kt * 64 + fn * 16 + lq) * kD + quad * 8;
      bf16x8 b0 = *(const bf16x8*)kp;
      bf16x8 b1 = *(const bf16x8*)(kp + 32);
      f32x4 acc = minit;
      acc = __builtin_amdgcn_mfma_f32_16x16x32_bf16(aq0, b0, acc, 0, 0, 0);
      acc = __builtin_amdgcn_mfma_f32_16x16x32_bf16(aq1, b1, acc, 0, 0, 0);
      s[fn] = acc;
    }
    // ---- p = exp2(s); vectorized P store (cols permuted: k' = lq*4+fn) ----
#pragma unroll
    for (int r = 0; r < 4; ++r) {
      const float p0 = __builtin_amdgcn_exp2f(s[0][r]);
      const float p1 = __builtin_amdgcn_exp2f(s[1][r]);
      const float p2 = __builtin_amdgcn_exp2f(s[2][r]);
      const float p3 = __builtin_amdgcn_exp2f(s[3][r]);
      lr[r] += (p0 + p1) + (p2 + p3);
      bf16x4 pk = {(__bf16)p0, (__bf16)p1, (__bf16)p2, (__bf16)p3};
      *(bf16x4*)&myP[(quad * 4 + r) * 72 + lq * 4] = pk;  // ds_write_b64
    }
    // ---- O += P V (A-frag reads, contiguous b128; V pre-permuted) ----
    bf16x8 ap0 = *(const bf16x8*)&myP[lq * 72 + quad * 8];
    bf16x8 ap1 = *(const bf16x8*)&myP[lq * 72 + 32 + quad * 8];
#pragma unroll
    for (int fn = 0; fn < 4; ++fn) {
      o[fn] = __builtin_amdgcn_mfma_f32_16x16x32_bf16(ap0, vb0[fn], o[fn], 0, 0, 0);
      o[fn] = __builtin_amdgcn_mfma_f32_16x16x32_bf16(ap1, vb1[fn], o[fn], 0, 0, 0);
    }
  }
  // ---- single end-of-block row-sum reduction over the 16 lanes of a row --
#pragma unroll
  for (int r = 0; r < 4; ++r) {
    float sum = lr[r];
#pragma unroll
    for (int off = 1; off < 16; off <<= 1) sum += __shfl_xor(sum, off, 64);
    lr[r] = sum;
  }
  const int b = bh >> 3, h = bh & 7;
  const int tok0 = b * kN + qt * 64 + w * 16 + quad * 4;
#pragma unroll
  for (int r = 0; r < 4; ++r) {
    const float inv = 1.f / lr[r];
#pragma unroll
    for (int fn = 0; fn < 4; ++fn)
      ao[(size_t)(tok0 + r) * kDim + h * 64 + fn * 16 + lq] = (__bf16)(o[fn][r] * inv);
  }
}

// ===========================================================================
extern "C" void kernel_launch(void* const* d_in, const int* in_sizes, int n_in,
                              void* d_out, int out_size, void* d_ws, size_t ws_size,
                              hipStream_t stream) {
  const float* x    = (const float*)d_in[0];
  const float* Wq   = (const float*)d_in[1];
  const float* Wkv  = (const float*)d_in[2];
  const float* Wout = (const float*)d_in[3];
  float* out = (float*)d_out;
  char* ws = (char*)d_ws;

  // Liveness-overlaid workspace (40 MB total):
  float*  q_f  = (float*)(ws);                       //  0..8M   fp32 [4096,512]
  float*  kv_f = (float*)(ws + (size_t)(8 << 20));   //  8..24M  fp32 [4096,1024]
  __bf16* qn   = (__bf16*)(ws + (size_t)(24 << 20)); // 24..28M  [bh][n][d]
  __bf16* kn   = (__bf16*)(ws + (size_t)(28 << 20)); // 28..32M  [bh][n][d]
  __bf16* vt   = (__bf16*)(ws + (size_t)(32 << 20)); // 32..36M  [bh][d][n-perm]
  __bf16* ao   = (__bf16*)(ws + (size_t)(36 << 20)); // 36..40M  [tok][dim]
  // overlays (dead before overwrite, stream-ordered):
  __bf16* xb   = (__bf16*)(ws + (size_t)(36 << 20)); // dies before ao written
  __bf16* wqb  = (__bf16*)(ws + (size_t)(24 << 20)); // dies before qn written
  __bf16* wkvb = (__bf16*)(ws + (size_t)(28 << 20)); // dies before kn written
  __bf16* wob  = (__bf16*)(ws + (size_t)(8 << 20));  // written after kv_f dead

  cvt_main<<<2816, 256, 0, stream>>>(x, Wq, Wkv, xb, wqb, wkvb);
  gemm_bt<<<dim3(8, 64),  256, 0, stream>>>(xb, wqb,  q_f,  kDim,     kDim);
  gemm_bt<<<dim3(16, 64), 256, 0, stream>>>(xb, wkvb, kv_f, 2 * kDim, kDim);
  norm_qk<<<kTok * kH / 4, 256, 0, stream>>>(q_f, kv_f, qn, kn);
  make_vt<<<dim3(kN / 64, kB * kH), 256, 0, stream>>>(kv_f, vt);
  cvt_wout<<<256, 256, 0, stream>>>(Wout, wob);
  attn_fused<<<dim3(kN / 64, kB * kH), 256, 0, stream>>>(qn, kn, vt, ao);
  gemm_bt<<<dim3(8, 64), 256, 0, stream>>>(ao, wob, out, kDim, kDim);
}

// Round 3
// 143.611 us; speedup vs baseline: 1.7271x; 1.5640x over previous
//
#include <hip/hip_runtime.h>

typedef __bf16 bf16x8 __attribute__((ext_vector_type(8)));
typedef __bf16 bf16x4 __attribute__((ext_vector_type(4)));
typedef float  f32x4  __attribute__((ext_vector_type(4)));

#define LOG2E_F 1.44269504088896340736f

static constexpr int kB = 2, kN = 2048, kH = 8, kD = 64, kDim = 512;
static constexpr int kTok = kB * kN;   // 4096
static constexpr int kNQKV = 1536;     // fused Wq(512)+Wkv(1024) rows

__device__ __forceinline__ void gld16(const void* g, void* l) {
  __builtin_amdgcn_global_load_lds(
      (const __attribute__((address_space(1))) void*)g,
      (__attribute__((address_space(3))) void*)l, 16, 0, 0);
}

// ===== fp32 -> bf16 linear converts: x | Wq | Wkv (fused) | Wout ===========
__global__ __launch_bounds__(256) void cvt_all(const float* __restrict__ x,
                                               const float* __restrict__ wq,
                                               const float* __restrict__ wkv,
                                               const float* __restrict__ wo,
                                               __bf16* __restrict__ xb,
                                               __bf16* __restrict__ wqkvb,
                                               __bf16* __restrict__ wob) {
  size_t i = ((size_t)blockIdx.x * 256 + threadIdx.x) * 8;
  const float* s; __bf16* d; size_t off;
  if (i < 2097152)      { s = x;   d = xb;              off = i; }
  else if (i < 2359296) { s = wq;  d = wqkvb;           off = i - 2097152; }
  else if (i < 2883584) { s = wkv; d = wqkvb + 262144;  off = i - 2359296; }
  else                  { s = wo;  d = wob;             off = i - 2883584; }
  float4 u = *(const float4*)(s + off);
  float4 v = *(const float4*)(s + off + 4);
  bf16x8 t;
  t[0] = (__bf16)u.x; t[1] = (__bf16)u.y; t[2] = (__bf16)u.z; t[3] = (__bf16)u.w;
  t[4] = (__bf16)v.x; t[5] = (__bf16)v.y; t[6] = (__bf16)v.z; t[7] = (__bf16)v.w;
  *(bf16x8*)(d + off) = t;
}

// ===== GEMM: C[M,N] = A[M,K]*B[N,K]^T, bf16 in, fp32 out ===================
// BM=128, BN=64, BK=64, double-buffered global_load_lds staging.
// 4 waves, each 32 rows x 64 cols (2x4 frags of 16x16x32).
__global__ __launch_bounds__(256, 3) void gemm128(const __bf16* __restrict__ A,
                                                  const __bf16* __restrict__ B,
                                                  float* __restrict__ C,
                                                  int N, int K) {
  const int tid = threadIdx.x;
  const int w = tid >> 6, lane = tid & 63, quad = lane >> 4, lq = lane & 15;
  const int m0 = blockIdx.y * 128;
  const int n0 = blockIdx.x * 64;
  const int wm = w * 32;
  __shared__ __bf16 As[2][128 * 64];
  __shared__ __bf16 Bs[2][64 * 64];

  const f32x4 zero = {0.f, 0.f, 0.f, 0.f};
  f32x4 acc[2][4];
#pragma unroll
  for (int fm = 0; fm < 2; ++fm)
#pragma unroll
    for (int fn = 0; fn < 4; ++fn) acc[fm][fn] = zero;

  const int sr = tid >> 3, sc = (tid & 7) << 3;
  auto stage = [&](int k0, int buf) {
#pragma unroll
    for (int j = 0; j < 4; ++j)
      gld16(A + (size_t)(m0 + j * 32 + sr) * K + k0 + sc,
            &As[buf][(size_t)(j * 32 + sr) * 64 + sc]);
#pragma unroll
    for (int j = 0; j < 2; ++j)
      gld16(B + (size_t)(n0 + j * 32 + sr) * K + k0 + sc,
            &Bs[buf][(size_t)(j * 32 + sr) * 64 + sc]);
  };

  stage(0, 0);
  const int iters = K >> 6;
  for (int i = 0; i < iters; ++i) {
    __syncthreads();
    if (i + 1 < iters) stage((i + 1) << 6, (i + 1) & 1);
    const __bf16* as = As[i & 1];
    const __bf16* bs = Bs[i & 1];
#pragma unroll
    for (int ks = 0; ks < 2; ++ks) {
      bf16x8 a[2], b[4];
#pragma unroll
      for (int fm = 0; fm < 2; ++fm)
        a[fm] = *(const bf16x8*)&as[(wm + fm * 16 + lq) * 64 + ks * 32 + quad * 8];
#pragma unroll
      for (int fn = 0; fn < 4; ++fn)
        b[fn] = *(const bf16x8*)&bs[(fn * 16 + lq) * 64 + ks * 32 + quad * 8];
#pragma unroll
      for (int fm = 0; fm < 2; ++fm)
#pragma unroll
        for (int fn = 0; fn < 4; ++fn)
          acc[fm][fn] =
              __builtin_amdgcn_mfma_f32_16x16x32_bf16(a[fm], b[fn], acc[fm][fn], 0, 0, 0);
    }
  }
#pragma unroll
  for (int fm = 0; fm < 2; ++fm)
#pragma unroll
    for (int fn = 0; fn < 4; ++fn)
#pragma unroll
      for (int r = 0; r < 4; ++r)
        C[(size_t)(m0 + wm + fm * 16 + quad * 4 + r) * N + n0 + fn * 16 + lq] =
            acc[fm][fn][r];
}

// ===== normalize q,k per (token, head) row of 64 ===========================
__global__ __launch_bounds__(256) void norm_qk(const float* __restrict__ qkv,
                                               __bf16* __restrict__ qn,
                                               __bf16* __restrict__ kn) {
  const int w    = blockIdx.x * 4 + (threadIdx.x >> 6);
  const int lane = threadIdx.x & 63;
  const int tok = w >> 3, h = w & 7;
  const int b = tok >> 11, n = tok & (kN - 1);
  const size_t dst = (((size_t)(b * kH + h) * kN) + n) * kD + lane;

  float v = qkv[(size_t)tok * kNQKV + h * 64 + lane];
  float ss = v * v;
#pragma unroll
  for (int m = 1; m < 64; m <<= 1) ss += __shfl_xor(ss, m, 64);
  float mag = sqrtf(ss * (1.f / 64)) + 1e-4f;
  qn[dst] = (__bf16)(v / mag * (0.125f * LOG2E_F));  // fold SCALE*log2e

  v = qkv[(size_t)tok * kNQKV + 512 + h * 64 + lane];
  ss = v * v;
#pragma unroll
  for (int m = 1; m < 64; m <<= 1) ss += __shfl_xor(ss, m, 64);
  mag = sqrtf(ss * (1.f / 64)) + 1e-4f;
  kn[dst] = (__bf16)(v / mag);
}

// ===== V -> vt2[bh][kt][d][64 key-permuted] (8KB tiles, staging-linear) ====
// position p holds key pi(p) = (p&3)*16 + (p>>2), matching P's A-frag order.
__global__ __launch_bounds__(256) void make_vt(const float* __restrict__ qkv,
                                               __bf16* __restrict__ vt2) {
  const int bh = blockIdx.y, b = bh >> 3, h = bh & 7;
  const int kt = blockIdx.x, n0 = kt * 64;
  __shared__ __bf16 tile[64][66];
  const int tl = threadIdx.x >> 6;
  const int d  = threadIdx.x & 63;
#pragma unroll
  for (int i = 0; i < 16; ++i) {
    const int n = i * 4 + tl;
    tile[d][n] = (__bf16)qkv[((size_t)(b * kN + n0 + n)) * kNQKV + 1024 + h * 64 + d];
  }
  __syncthreads();
  const int dr = threadIdx.x >> 2;
  const int c0 = (threadIdx.x & 3) * 16;
  const size_t base = ((size_t)(bh * 32 + kt) * 64 + dr) * 64 + c0;
#pragma unroll
  for (int i = 0; i < 16; ++i) {
    const int p = c0 + i;
    vt2[base + i] = tile[dr][((p & 3) << 4) + (p >> 2)];
  }
}

// ===== fused attention: block = (bh, 128-q tile, key-half) =================
// K/V tiles staged to LDS (double-buffered gld16); wave owns 32 q rows.
// Fixed-max softmax (bias -12 folded into MFMA C-init); fp32 partials out.
__global__ __launch_bounds__(256, 2) void attn(const __bf16* __restrict__ qn,
                                               const __bf16* __restrict__ kn,
                                               const __bf16* __restrict__ vt2,
                                               float* __restrict__ po,
                                               float* __restrict__ pl) {
  const int qt = blockIdx.x, bh = blockIdx.y, kh = blockIdx.z;
  const int tid = threadIdx.x;
  const int w = tid >> 6, lane = tid & 63, quad = lane >> 4, lq = lane & 15;
  __shared__ __bf16 Ks[2][4096];
  __shared__ __bf16 Vs[2][4096];
  __shared__ __bf16 Ps[4][32 * 72];
  __bf16* myP = Ps[w];

  // Q fragments: rows qt*128 + w*32 + fm*16 + lq (loaded once)
  bf16x8 aq[2][2];
#pragma unroll
  for (int fm = 0; fm < 2; ++fm) {
    const __bf16* Qb = qn + ((size_t)bh * kN + qt * 128 + w * 32 + fm * 16 + lq) * kD;
    aq[fm][0] = *(const bf16x8*)(Qb + quad * 8);
    aq[fm][1] = *(const bf16x8*)(Qb + 32 + quad * 8);
  }

  const f32x4 zero  = {0.f, 0.f, 0.f, 0.f};
  const f32x4 minit = {-12.f, -12.f, -12.f, -12.f};
  f32x4 o[2][4];
  float lr[2][4];
#pragma unroll
  for (int fm = 0; fm < 2; ++fm)
#pragma unroll
    for (int i = 0; i < 4; ++i) { o[fm][i] = zero; lr[fm][i] = 0.f; }

  const __bf16* Kb = kn + ((size_t)bh * kN + kh * 1024) * kD;
  const __bf16* Vb = vt2 + (size_t)(bh * 32 + kh * 16) * 4096;

  auto stage = [&](int kt, int buf) {
#pragma unroll
    for (int j = 0; j < 2; ++j) {
      gld16(Kb + (size_t)kt * 4096 + (j * 256 + tid) * 8, &Ks[buf][(j * 256 + tid) * 8]);
      gld16(Vb + (size_t)kt * 4096 + (j * 256 + tid) * 8, &Vs[buf][(j * 256 + tid) * 8]);
    }
  };

  stage(0, 0);
  for (int kt = 0; kt < 16; ++kt) {
    __syncthreads();
    if (kt < 15) stage(kt + 1, (kt + 1) & 1);
    const __bf16* ks_ = Ks[kt & 1];
    const __bf16* vs_ = Vs[kt & 1];

    // ---- S = Q K^T - 12 ----
    bf16x8 kb0[4], kb1[4];
#pragma unroll
    for (int fn = 0; fn < 4; ++fn) {
      const int row = fn * 16 + lq;
      kb0[fn] = *(const bf16x8*)&ks_[row * 64 + quad * 8];
      kb1[fn] = *(const bf16x8*)&ks_[row * 64 + 32 + quad * 8];
    }
    f32x4 s[2][4];
#pragma unroll
    for (int fm = 0; fm < 2; ++fm)
#pragma unroll
      for (int fn = 0; fn < 4; ++fn) {
        f32x4 a = __builtin_amdgcn_mfma_f32_16x16x32_bf16(aq[fm][0], kb0[fn], minit, 0, 0, 0);
        s[fm][fn] = __builtin_amdgcn_mfma_f32_16x16x32_bf16(aq[fm][1], kb1[fn], a, 0, 0, 0);
      }

    // ---- V fragments (shared LDS tile) ----
    bf16x8 vb0[4], vb1[4];
#pragma unroll
    for (int fn = 0; fn < 4; ++fn) {
      const int row = fn * 16 + lq;
      vb0[fn] = *(const bf16x8*)&vs_[row * 64 + quad * 8];
      vb1[fn] = *(const bf16x8*)&vs_[row * 64 + 32 + quad * 8];
    }

    // ---- p = exp2(s); P into per-wave LDS in A-frag (key-permuted) order --
#pragma unroll
    for (int fm = 0; fm < 2; ++fm)
#pragma unroll
      for (int r = 0; r < 4; ++r) {
        const float p0 = __builtin_amdgcn_exp2f(s[fm][0][r]);
        const float p1 = __builtin_amdgcn_exp2f(s[fm][1][r]);
        const float p2 = __builtin_amdgcn_exp2f(s[fm][2][r]);
        const float p3 = __builtin_amdgcn_exp2f(s[fm][3][r]);
        lr[fm][r] += (p0 + p1) + (p2 + p3);
        bf16x4 pk = {(__bf16)p0, (__bf16)p1, (__bf16)p2, (__bf16)p3};
        *(bf16x4*)&myP[(fm * 16 + quad * 4 + r) * 72 + lq * 4] = pk;
      }

    // ---- O += P V ----
#pragma unroll
    for (int fm = 0; fm < 2; ++fm) {
      bf16x8 ap0 = *(const bf16x8*)&myP[(fm * 16 + lq) * 72 + quad * 8];
      bf16x8 ap1 = *(const bf16x8*)&myP[(fm * 16 + lq) * 72 + 32 + quad * 8];
#pragma unroll
      for (int fn = 0; fn < 4; ++fn) {
        o[fm][fn] = __builtin_amdgcn_mfma_f32_16x16x32_bf16(ap0, vb0[fn], o[fm][fn], 0, 0, 0);
        o[fm][fn] = __builtin_amdgcn_mfma_f32_16x16x32_bf16(ap1, vb1[fn], o[fm][fn], 0, 0, 0);
      }
    }
  }

  // ---- epilogue: fp32 partials (no normalization yet) ----
  const int b = bh >> 3, h = bh & 7;
#pragma unroll
  for (int fm = 0; fm < 2; ++fm) {
    const int qrow0 = qt * 128 + w * 32 + fm * 16 + quad * 4;
#pragma unroll
    for (int r = 0; r < 4; ++r) {
      float sum = lr[fm][r];
#pragma unroll
      for (int off = 1; off < 16; off <<= 1) sum += __shfl_xor(sum, off, 64);
      if (lq == 0) pl[(size_t)kh * 32768 + bh * kN + qrow0 + r] = sum;
      const size_t ob = ((size_t)kh * kTok + b * kN + qrow0 + r) * kDim + h * 64;
#pragma unroll
      for (int fn = 0; fn < 4; ++fn) po[ob + fn * 16 + lq] = o[fm][fn][r];
    }
  }
}

// ===== combine halves: ao = (o0+o1)/(l0+l1), bf16 ==========================
__global__ __launch_bounds__(256) void combine(const float* __restrict__ po,
                                               const float* __restrict__ pl,
                                               __bf16* __restrict__ ao) {
  const size_t i = ((size_t)blockIdx.x * 256 + threadIdx.x) * 4;
  const int tok = (int)(i >> 9), dk = (int)(i & 511);
  const int h = dk >> 6, b = tok >> 11, qrow = tok & (kN - 1);
  const int bh = b * kH + h;
  const float l = pl[bh * kN + qrow] + pl[32768 + bh * kN + qrow];
  const float inv = 1.f / l;
  float4 a = *(const float4*)(po + i);
  float4 c = *(const float4*)(po + (size_t)kTok * kDim + i);
  bf16x4 t = {(__bf16)((a.x + c.x) * inv), (__bf16)((a.y + c.y) * inv),
              (__bf16)((a.z + c.z) * inv), (__bf16)((a.w + c.w) * inv)};
  *(bf16x4*)(ao + i) = t;
}

// ===========================================================================
extern "C" void kernel_launch(void* const* d_in, const int* in_sizes, int n_in,
                              void* d_out, int out_size, void* d_ws, size_t ws_size,
                              hipStream_t stream) {
  const float* x    = (const float*)d_in[0];
  const float* Wq   = (const float*)d_in[1];
  const float* Wkv  = (const float*)d_in[2];
  const float* Wout = (const float*)d_in[3];
  float* out = (float*)d_out;
  char* ws = (char*)d_ws;

  // Liveness-overlaid workspace (max 36.5 MB used):
  float*  qkv_f = (float*)(ws);                        //  0..24M fp32 [4096,1536]
  __bf16* qn    = (__bf16*)(ws + (size_t)(24 << 20));  // 24..28M [bh][n][d]
  __bf16* kn    = (__bf16*)(ws + (size_t)(28 << 20));  // 28..32M [bh][n][d]
  __bf16* vt2   = (__bf16*)(ws + (size_t)(32 << 20));  // 32..36M tiled V^T
  __bf16* wob   = (__bf16*)(ws + (size_t)(36 << 20));  // 36..36.5M (lives to end)
  // overlays (stream-ordered liveness):
  __bf16* xb    = (__bf16*)(ws + (size_t)(24 << 20));  // dead before qn written
  __bf16* wqkvb = (__bf16*)(ws + (size_t)(28 << 20));  // dead before kn written
  float*  po    = (float*)(ws);                        //  0..16M (qkv_f dead)
  float*  pl    = (float*)(ws + (size_t)(16 << 20));   // 16..16.25M
  __bf16* ao    = (__bf16*)(ws + (size_t)(17 << 20));  // 17..21M

  cvt_all<<<1536, 256, 0, stream>>>(x, Wq, Wkv, Wout, xb, wqkvb, wob);
  gemm128<<<dim3(kNQKV / 64, kTok / 128), 256, 0, stream>>>(xb, wqkvb, qkv_f,
                                                            kNQKV, kDim);
  norm_qk<<<kTok * kH / 4, 256, 0, stream>>>(qkv_f, qn, kn);
  make_vt<<<dim3(kN / 64, kB * kH), 256, 0, stream>>>(qkv_f, vt2);
  attn<<<dim3(kN / 128, kB * kH, 2), 256, 0, stream>>>(qn, kn, vt2, po, pl);
  combine<<<kTok * kDim / 1024, 256, 0, stream>>>(po, pl, ao);
  gemm128<<<dim3(kDim / 64, kTok / 128), 256, 0, stream>>>(ao, wob, out, kDim, kDim);
}

// Round 4
// 130.357 us; speedup vs baseline: 1.9027x; 1.1017x over previous
//
#include <hip/hip_runtime.h>

typedef __bf16 bf16x8 __attribute__((ext_vector_type(8)));
typedef __bf16 bf16x4 __attribute__((ext_vector_type(4)));
typedef float  f32x4  __attribute__((ext_vector_type(4)));

#define LOG2E_F 1.44269504088896340736f

static constexpr int kB = 2, kN = 2048, kH = 8, kD = 64, kDim = 512;
static constexpr int kTok = kB * kN;   // 4096
static constexpr int kNQKV = 1536;     // fused Wq(512)+Wkv(1024) rows

__device__ __forceinline__ void gld16(const void* g, void* l) {
  __builtin_amdgcn_global_load_lds(
      (const __attribute__((address_space(1))) void*)g,
      (__attribute__((address_space(3))) void*)l, 16, 0, 0);
}

// ===== fp32 -> bf16 linear converts: x | Wq | Wkv (fused) | Wout ===========
__global__ __launch_bounds__(256) void cvt_all(const float* __restrict__ x,
                                               const float* __restrict__ wq,
                                               const float* __restrict__ wkv,
                                               const float* __restrict__ wo,
                                               __bf16* __restrict__ xb,
                                               __bf16* __restrict__ wqkvb,
                                               __bf16* __restrict__ wob) {
  size_t i = ((size_t)blockIdx.x * 256 + threadIdx.x) * 8;
  const float* s; __bf16* d; size_t off;
  if (i < 2097152)      { s = x;   d = xb;              off = i; }
  else if (i < 2359296) { s = wq;  d = wqkvb;           off = i - 2097152; }
  else if (i < 2883584) { s = wkv; d = wqkvb + 262144;  off = i - 2359296; }
  else                  { s = wo;  d = wob;             off = i - 2883584; }
  float4 u = *(const float4*)(s + off);
  float4 v = *(const float4*)(s + off + 4);
  bf16x8 t;
  t[0] = (__bf16)u.x; t[1] = (__bf16)u.y; t[2] = (__bf16)u.z; t[3] = (__bf16)u.w;
  t[4] = (__bf16)v.x; t[5] = (__bf16)v.y; t[6] = (__bf16)v.z; t[7] = (__bf16)v.w;
  *(bf16x8*)(d + off) = t;
}

// ===== QKV GEMM with fused norm/transpose epilogue =========================
// C = xb[4096,512] * wqkvb[1536,512]^T. BM=128, BN=64 (= exactly one head's
// 64 dims), BK=64, double-buffered gld16 staging. Epilogue:
//   n0<512   : q -> rms-normalize * SCALE*log2e -> qn[bh][n][d] bf16
//   512..1023: k -> rms-normalize              -> kn[bh][n][d] bf16
//   >=1024   : v -> vt2[bh][kt][d][p] (transposed, key-permuted) bf16
__global__ __launch_bounds__(256, 3) void gemm_qkv(const __bf16* __restrict__ A,
                                                   const __bf16* __restrict__ B,
                                                   __bf16* __restrict__ qn,
                                                   __bf16* __restrict__ kn,
                                                   __bf16* __restrict__ vt2) {
  const int K = kDim;
  const int tid = threadIdx.x;
  const int w = tid >> 6, lane = tid & 63, quad = lane >> 4, lq = lane & 15;
  const int m0 = blockIdx.y * 128;
  const int n0 = blockIdx.x * 64;
  const int wm = w * 32;
  __shared__ __bf16 As[2][128 * 64];
  __shared__ __bf16 Bs[2][64 * 64];

  const f32x4 zero = {0.f, 0.f, 0.f, 0.f};
  f32x4 acc[2][4];
#pragma unroll
  for (int fm = 0; fm < 2; ++fm)
#pragma unroll
    for (int fn = 0; fn < 4; ++fn) acc[fm][fn] = zero;

  const int sr = tid >> 3, sc = (tid & 7) << 3;
  auto stage = [&](int k0, int buf) {
#pragma unroll
    for (int j = 0; j < 4; ++j)
      gld16(A + (size_t)(m0 + j * 32 + sr) * K + k0 + sc,
            &As[buf][(size_t)(j * 32 + sr) * 64 + sc]);
#pragma unroll
    for (int j = 0; j < 2; ++j)
      gld16(B + (size_t)(n0 + j * 32 + sr) * K + k0 + sc,
            &Bs[buf][(size_t)(j * 32 + sr) * 64 + sc]);
  };

  stage(0, 0);
  for (int i = 0; i < 8; ++i) {
    __syncthreads();
    if (i + 1 < 8) stage((i + 1) << 6, (i + 1) & 1);
    const __bf16* as = As[i & 1];
    const __bf16* bs = Bs[i & 1];
#pragma unroll
    for (int ks = 0; ks < 2; ++ks) {
      bf16x8 a[2], b[4];
#pragma unroll
      for (int fm = 0; fm < 2; ++fm)
        a[fm] = *(const bf16x8*)&as[(wm + fm * 16 + lq) * 64 + ks * 32 + quad * 8];
#pragma unroll
      for (int fn = 0; fn < 4; ++fn)
        b[fn] = *(const bf16x8*)&bs[(fn * 16 + lq) * 64 + ks * 32 + quad * 8];
#pragma unroll
      for (int fm = 0; fm < 2; ++fm)
#pragma unroll
        for (int fn = 0; fn < 4; ++fn)
          acc[fm][fn] =
              __builtin_amdgcn_mfma_f32_16x16x32_bf16(a[fm], b[fn], acc[fm][fn], 0, 0, 0);
    }
  }

  const int h = (n0 >> 6) & 7;  // head within q / k / v section
  if (n0 >= 1024) {
    // ---- V: transpose + key-permute scatter (no norm) ----
#pragma unroll
    for (int fm = 0; fm < 2; ++fm)
#pragma unroll
      for (int r = 0; r < 4; ++r) {
        const int m = m0 + wm + fm * 16 + quad * 4 + r;
        const int b = m >> 11, n = m & (kN - 1);
        const int kt = n >> 6, tt = n & 63;
        const int p = (tt & 15) * 4 + (tt >> 4);  // inverse of attn's pi
        const size_t base = (size_t)(((b * kH + h) * 32 + kt) * 64) * 64 + p;
#pragma unroll
        for (int fn = 0; fn < 4; ++fn)
          vt2[base + (size_t)(fn * 16 + lq) * 64] = (__bf16)acc[fm][fn][r];
      }
  } else {
    // ---- Q/K: rms over the 64 cols (4 frags x 16 lq lanes) ----
    const float qs = (n0 < 512) ? (0.125f * LOG2E_F) : 1.0f;
    __bf16* dst0 = (n0 < 512) ? qn : kn;
#pragma unroll
    for (int fm = 0; fm < 2; ++fm)
#pragma unroll
      for (int r = 0; r < 4; ++r) {
        float ss = 0.f;
#pragma unroll
        for (int fn = 0; fn < 4; ++fn) ss += acc[fm][fn][r] * acc[fm][fn][r];
#pragma unroll
        for (int off = 1; off < 16; off <<= 1) ss += __shfl_xor(ss, off, 64);
        const float inv = qs / (sqrtf(ss * (1.f / 64)) + 1e-4f);
        const int m = m0 + wm + fm * 16 + quad * 4 + r;
        const int b = m >> 11, n = m & (kN - 1);
        __bf16* dst = dst0 + ((size_t)(b * kH + h) * kN + n) * kD;
#pragma unroll
        for (int fn = 0; fn < 4; ++fn)
          dst[fn * 16 + lq] = (__bf16)(acc[fm][fn][r] * inv);
      }
  }
}

// ===== fused attention: block = (128-q tile, bh, key-half) =================
// K/V tiles staged to LDS (double-buffered gld16); wave owns 32 q rows.
// Fixed-max softmax (scores bounded: |s| <= 8*SCALE*log2e < 12; bias -12
// folded into MFMA C-init). bf16 partials + fp32 row-sums out.
__global__ __launch_bounds__(256, 2) void attn(const __bf16* __restrict__ qn,
                                               const __bf16* __restrict__ kn,
                                               const __bf16* __restrict__ vt2,
                                               __bf16* __restrict__ po,
                                               float* __restrict__ pl) {
  const int qt = blockIdx.x, bh = blockIdx.y, kh = blockIdx.z;
  const int tid = threadIdx.x;
  const int w = tid >> 6, lane = tid & 63, quad = lane >> 4, lq = lane & 15;
  __shared__ __bf16 Ks[2][4096];
  __shared__ __bf16 Vs[2][4096];
  __shared__ __bf16 Ps[4][32 * 72];
  __bf16* myP = Ps[w];

  bf16x8 aq[2][2];
#pragma unroll
  for (int fm = 0; fm < 2; ++fm) {
    const __bf16* Qb = qn + ((size_t)bh * kN + qt * 128 + w * 32 + fm * 16 + lq) * kD;
    aq[fm][0] = *(const bf16x8*)(Qb + quad * 8);
    aq[fm][1] = *(const bf16x8*)(Qb + 32 + quad * 8);
  }

  const f32x4 zero  = {0.f, 0.f, 0.f, 0.f};
  const f32x4 minit = {-12.f, -12.f, -12.f, -12.f};
  f32x4 o[2][4];
  float lr[2][4];
#pragma unroll
  for (int fm = 0; fm < 2; ++fm)
#pragma unroll
    for (int i = 0; i < 4; ++i) { o[fm][i] = zero; lr[fm][i] = 0.f; }

  const __bf16* Kb = kn + ((size_t)bh * kN + kh * 1024) * kD;
  const __bf16* Vb = vt2 + (size_t)(bh * 32 + kh * 16) * 4096;

  auto stage = [&](int kt, int buf) {
#pragma unroll
    for (int j = 0; j < 2; ++j) {
      gld16(Kb + (size_t)kt * 4096 + (j * 256 + tid) * 8, &Ks[buf][(j * 256 + tid) * 8]);
      gld16(Vb + (size_t)kt * 4096 + (j * 256 + tid) * 8, &Vs[buf][(j * 256 + tid) * 8]);
    }
  };

  stage(0, 0);
#pragma unroll 2
  for (int kt = 0; kt < 16; ++kt) {
    __syncthreads();
    if (kt < 15) stage(kt + 1, (kt + 1) & 1);
    const __bf16* ks_ = Ks[kt & 1];
    const __bf16* vs_ = Vs[kt & 1];

    bf16x8 kb0[4], kb1[4], vb0[4], vb1[4];
#pragma unroll
    for (int fn = 0; fn < 4; ++fn) {
      const int row = fn * 16 + lq;
      kb0[fn] = *(const bf16x8*)&ks_[row * 64 + quad * 8];
      kb1[fn] = *(const bf16x8*)&ks_[row * 64 + 32 + quad * 8];
      vb0[fn] = *(const bf16x8*)&vs_[row * 64 + quad * 8];
      vb1[fn] = *(const bf16x8*)&vs_[row * 64 + 32 + quad * 8];
    }
    f32x4 s[2][4];
#pragma unroll
    for (int fm = 0; fm < 2; ++fm)
#pragma unroll
      for (int fn = 0; fn < 4; ++fn) {
        f32x4 a = __builtin_amdgcn_mfma_f32_16x16x32_bf16(aq[fm][0], kb0[fn], minit, 0, 0, 0);
        s[fm][fn] = __builtin_amdgcn_mfma_f32_16x16x32_bf16(aq[fm][1], kb1[fn], a, 0, 0, 0);
      }

#pragma unroll
    for (int fm = 0; fm < 2; ++fm)
#pragma unroll
      for (int r = 0; r < 4; ++r) {
        const float p0 = __builtin_amdgcn_exp2f(s[fm][0][r]);
        const float p1 = __builtin_amdgcn_exp2f(s[fm][1][r]);
        const float p2 = __builtin_amdgcn_exp2f(s[fm][2][r]);
        const float p3 = __builtin_amdgcn_exp2f(s[fm][3][r]);
        lr[fm][r] += (p0 + p1) + (p2 + p3);
        bf16x4 pk = {(__bf16)p0, (__bf16)p1, (__bf16)p2, (__bf16)p3};
        *(bf16x4*)&myP[(fm * 16 + quad * 4 + r) * 72 + lq * 4] = pk;
      }

#pragma unroll
    for (int fm = 0; fm < 2; ++fm) {
      bf16x8 ap0 = *(const bf16x8*)&myP[(fm * 16 + lq) * 72 + quad * 8];
      bf16x8 ap1 = *(const bf16x8*)&myP[(fm * 16 + lq) * 72 + 32 + quad * 8];
#pragma unroll
      for (int fn = 0; fn < 4; ++fn) {
        o[fm][fn] = __builtin_amdgcn_mfma_f32_16x16x32_bf16(ap0, vb0[fn], o[fm][fn], 0, 0, 0);
        o[fm][fn] = __builtin_amdgcn_mfma_f32_16x16x32_bf16(ap1, vb1[fn], o[fm][fn], 0, 0, 0);
      }
    }
  }

  const int b = bh >> 3, h = bh & 7;
#pragma unroll
  for (int fm = 0; fm < 2; ++fm) {
    const int qrow0 = qt * 128 + w * 32 + fm * 16 + quad * 4;
#pragma unroll
    for (int r = 0; r < 4; ++r) {
      float sum = lr[fm][r];
#pragma unroll
      for (int off = 1; off < 16; off <<= 1) sum += __shfl_xor(sum, off, 64);
      if (lq == 0) pl[(size_t)kh * 32768 + bh * kN + qrow0 + r] = sum;
      const size_t ob = ((size_t)kh * kTok + b * kN + qrow0 + r) * kDim + h * 64;
#pragma unroll
      for (int fn = 0; fn < 4; ++fn) po[ob + fn * 16 + lq] = (__bf16)o[fm][fn][r];
    }
  }
}

// ===== combine halves: ao = (o0+o1)/(l0+l1), bf16 ==========================
__global__ __launch_bounds__(256) void combine(const __bf16* __restrict__ po,
                                               const float* __restrict__ pl,
                                               __bf16* __restrict__ ao) {
  const size_t i = ((size_t)blockIdx.x * 256 + threadIdx.x) * 4;
  const int tok = (int)(i >> 9), dk = (int)(i & 511);
  const int h = dk >> 6, b = tok >> 11, qrow = tok & (kN - 1);
  const int bh = b * kH + h;
  const float l = pl[bh * kN + qrow] + pl[32768 + bh * kN + qrow];
  const float inv = 1.f / l;
  bf16x4 a = *(const bf16x4*)(po + i);
  bf16x4 c = *(const bf16x4*)(po + (size_t)kTok * kDim + i);
  bf16x4 t = {(__bf16)(((float)a[0] + (float)c[0]) * inv),
              (__bf16)(((float)a[1] + (float)c[1]) * inv),
              (__bf16)(((float)a[2] + (float)c[2]) * inv),
              (__bf16)(((float)a[3] + (float)c[3]) * inv)};
  *(bf16x4*)(ao + i) = t;
}

// ===== out-proj GEMM: C[M,N] = A*B^T, bf16 in, fp32 out ====================
__global__ __launch_bounds__(256, 3) void gemm128(const __bf16* __restrict__ A,
                                                  const __bf16* __restrict__ B,
                                                  float* __restrict__ C,
                                                  int N, int K) {
  const int tid = threadIdx.x;
  const int w = tid >> 6, lane = tid & 63, quad = lane >> 4, lq = lane & 15;
  const int m0 = blockIdx.y * 128;
  const int n0 = blockIdx.x * 64;
  const int wm = w * 32;
  __shared__ __bf16 As[2][128 * 64];
  __shared__ __bf16 Bs[2][64 * 64];

  const f32x4 zero = {0.f, 0.f, 0.f, 0.f};
  f32x4 acc[2][4];
#pragma unroll
  for (int fm = 0; fm < 2; ++fm)
#pragma unroll
    for (int fn = 0; fn < 4; ++fn) acc[fm][fn] = zero;

  const int sr = tid >> 3, sc = (tid & 7) << 3;
  auto stage = [&](int k0, int buf) {
#pragma unroll
    for (int j = 0; j < 4; ++j)
      gld16(A + (size_t)(m0 + j * 32 + sr) * K + k0 + sc,
            &As[buf][(size_t)(j * 32 + sr) * 64 + sc]);
#pragma unroll
    for (int j = 0; j < 2; ++j)
      gld16(B + (size_t)(n0 + j * 32 + sr) * K + k0 + sc,
            &Bs[buf][(size_t)(j * 32 + sr) * 64 + sc]);
  };

  stage(0, 0);
  const int iters = K >> 6;
  for (int i = 0; i < iters; ++i) {
    __syncthreads();
    if (i + 1 < iters) stage((i + 1) << 6, (i + 1) & 1);
    const __bf16* as = As[i & 1];
    const __bf16* bs = Bs[i & 1];
#pragma unroll
    for (int ks = 0; ks < 2; ++ks) {
      bf16x8 a[2], b[4];
#pragma unroll
      for (int fm = 0; fm < 2; ++fm)
        a[fm] = *(const bf16x8*)&as[(wm + fm * 16 + lq) * 64 + ks * 32 + quad * 8];
#pragma unroll
      for (int fn = 0; fn < 4; ++fn)
        b[fn] = *(const bf16x8*)&bs[(fn * 16 + lq) * 64 + ks * 32 + quad * 8];
#pragma unroll
      for (int fm = 0; fm < 2; ++fm)
#pragma unroll
        for (int fn = 0; fn < 4; ++fn)
          acc[fm][fn] =
              __builtin_amdgcn_mfma_f32_16x16x32_bf16(a[fm], b[fn], acc[fm][fn], 0, 0, 0);
    }
  }
#pragma unroll
  for (int fm = 0; fm < 2; ++fm)
#pragma unroll
    for (int fn = 0; fn < 4; ++fn)
#pragma unroll
      for (int r = 0; r < 4; ++r)
        C[(size_t)(m0 + wm + fm * 16 + quad * 4 + r) * N + n0 + fn * 16 + lq] =
            acc[fm][fn][r];
}

// ===========================================================================
extern "C" void kernel_launch(void* const* d_in, const int* in_sizes, int n_in,
                              void* d_out, int out_size, void* d_ws, size_t ws_size,
                              hipStream_t stream) {
  const float* x    = (const float*)d_in[0];
  const float* Wq   = (const float*)d_in[1];
  const float* Wkv  = (const float*)d_in[2];
  const float* Wout = (const float*)d_in[3];
  float* out = (float*)d_out;
  char* ws = (char*)d_ws;

  // Flat workspace, no overlays (32 MB):
  __bf16* xb    = (__bf16*)(ws);                       //  0..4M   [4096,512]
  __bf16* wqkvb = (__bf16*)(ws + (size_t)(4 << 20));   //  4..5.5M [1536,512]
  __bf16* wob   = (__bf16*)(ws + (size_t)(6 << 20));   //  6..6.5M [512,512]
  __bf16* qn    = (__bf16*)(ws + (size_t)(7 << 20));   //  7..11M  [bh][n][d]
  __bf16* kn    = (__bf16*)(ws + (size_t)(11 << 20));  // 11..15M  [bh][n][d]
  __bf16* vt2   = (__bf16*)(ws + (size_t)(15 << 20));  // 15..19M  tiled V^T
  __bf16* po    = (__bf16*)(ws + (size_t)(19 << 20));  // 19..27M  partials x2
  float*  pl    = (float*)(ws + (size_t)(27 << 20));   // 27..27.25M
  __bf16* ao    = (__bf16*)(ws + (size_t)(28 << 20));  // 28..32M  [tok][dim]

  cvt_all<<<1536, 256, 0, stream>>>(x, Wq, Wkv, Wout, xb, wqkvb, wob);
  gemm_qkv<<<dim3(kNQKV / 64, kTok / 128), 256, 0, stream>>>(xb, wqkvb, qn, kn, vt2);
  attn<<<dim3(kN / 128, kB * kH, 2), 256, 0, stream>>>(qn, kn, vt2, po, pl);
  combine<<<kTok * kDim / 1024, 256, 0, stream>>>(po, pl, ao);
  gemm128<<<dim3(kDim / 64, kTok / 128), 256, 0, stream>>>(ao, wob, out, kDim, kDim);
}

// Round 5
// 129.742 us; speedup vs baseline: 1.9117x; 1.0047x over previous
//
#include <hip/hip_runtime.h>

typedef __bf16 bf16x8 __attribute__((ext_vector_type(8)));
typedef __bf16 bf16x4 __attribute__((ext_vector_type(4)));
typedef float  f32x4  __attribute__((ext_vector_type(4)));

#define LOG2E_F 1.44269504088896340736f

static constexpr int kB = 2, kN = 2048, kH = 8, kD = 64, kDim = 512;
static constexpr int kTok = kB * kN;   // 4096
static constexpr int kNQKV = 1536;     // fused Wq(512)+Wkv(1024) rows
static constexpr int kKH = 4;          // attention split-K factor (512 keys each)

__device__ __forceinline__ void gld16(const void* g, void* l) {
  __builtin_amdgcn_global_load_lds(
      (const __attribute__((address_space(1))) void*)g,
      (__attribute__((address_space(3))) void*)l, 16, 0, 0);
}

// ===== fp32 -> bf16 linear converts: x | Wq | Wkv (fused) | Wout ===========
__global__ __launch_bounds__(256) void cvt_all(const float* __restrict__ x,
                                               const float* __restrict__ wq,
                                               const float* __restrict__ wkv,
                                               const float* __restrict__ wo,
                                               __bf16* __restrict__ xb,
                                               __bf16* __restrict__ wqkvb,
                                               __bf16* __restrict__ wob) {
  size_t i = ((size_t)blockIdx.x * 256 + threadIdx.x) * 8;
  const float* s; __bf16* d; size_t off;
  if (i < 2097152)      { s = x;   d = xb;              off = i; }
  else if (i < 2359296) { s = wq;  d = wqkvb;           off = i - 2097152; }
  else if (i < 2883584) { s = wkv; d = wqkvb + 262144;  off = i - 2359296; }
  else                  { s = wo;  d = wob;             off = i - 2883584; }
  float4 u = *(const float4*)(s + off);
  float4 v = *(const float4*)(s + off + 4);
  bf16x8 t;
  t[0] = (__bf16)u.x; t[1] = (__bf16)u.y; t[2] = (__bf16)u.z; t[3] = (__bf16)u.w;
  t[4] = (__bf16)v.x; t[5] = (__bf16)v.y; t[6] = (__bf16)v.z; t[7] = (__bf16)v.w;
  *(bf16x8*)(d + off) = t;
}

// ===== QKV GEMM with fused norm/transpose epilogue =========================
// C = xb[4096,512] * wqkvb[1536,512]^T. BM=128, BN=64 (one head's 64 dims),
// BK=64, double-buffered gld16 staging. Epilogue:
//   n0<512   : q -> rms-normalize * SCALE*log2e -> qn[bh][n][d] bf16
//   512..1023: k -> rms-normalize               -> kn[bh][n][d] bf16
//   >=1024   : v -> LDS transpose -> vt2[bh][kt][d][p] coalesced 16B stores
__global__ __launch_bounds__(256, 3) void gemm_qkv(const __bf16* __restrict__ A,
                                                   const __bf16* __restrict__ B,
                                                   __bf16* __restrict__ qn,
                                                   __bf16* __restrict__ kn,
                                                   __bf16* __restrict__ vt2) {
  const int K = kDim;
  const int tid = threadIdx.x;
  const int w = tid >> 6, lane = tid & 63, quad = lane >> 4, lq = lane & 15;
  const int m0 = blockIdx.y * 128;
  const int n0 = blockIdx.x * 64;
  const int wm = w * 32;
  __shared__ __bf16 As[2][128 * 64];
  __shared__ __bf16 Bs[2][64 * 64];

  const f32x4 zero = {0.f, 0.f, 0.f, 0.f};
  f32x4 acc[2][4];
#pragma unroll
  for (int fm = 0; fm < 2; ++fm)
#pragma unroll
    for (int fn = 0; fn < 4; ++fn) acc[fm][fn] = zero;

  const int sr = tid >> 3, sc = (tid & 7) << 3;
  auto stage = [&](int k0, int buf) {
#pragma unroll
    for (int j = 0; j < 4; ++j)
      gld16(A + (size_t)(m0 + j * 32 + sr) * K + k0 + sc,
            &As[buf][(size_t)(j * 32 + sr) * 64 + sc]);
#pragma unroll
    for (int j = 0; j < 2; ++j)
      gld16(B + (size_t)(n0 + j * 32 + sr) * K + k0 + sc,
            &Bs[buf][(size_t)(j * 32 + sr) * 64 + sc]);
  };

  stage(0, 0);
  for (int i = 0; i < 8; ++i) {
    __syncthreads();
    if (i + 1 < 8) stage((i + 1) << 6, (i + 1) & 1);
    const __bf16* as = As[i & 1];
    const __bf16* bs = Bs[i & 1];
#pragma unroll
    for (int ks = 0; ks < 2; ++ks) {
      bf16x8 a[2], b[4];
#pragma unroll
      for (int fm = 0; fm < 2; ++fm)
        a[fm] = *(const bf16x8*)&as[(wm + fm * 16 + lq) * 64 + ks * 32 + quad * 8];
#pragma unroll
      for (int fn = 0; fn < 4; ++fn)
        b[fn] = *(const bf16x8*)&bs[(fn * 16 + lq) * 64 + ks * 32 + quad * 8];
#pragma unroll
      for (int fm = 0; fm < 2; ++fm)
#pragma unroll
        for (int fn = 0; fn < 4; ++fn)
          acc[fm][fn] =
              __builtin_amdgcn_mfma_f32_16x16x32_bf16(a[fm], b[fn], acc[fm][fn], 0, 0, 0);
    }
  }

  const int h = (n0 >> 6) & 7;  // head within q / k / v section
  if (n0 >= 1024) {
    // ---- V: transpose via LDS (reuse As), then coalesced 16B stores ----
    __syncthreads();  // all waves done reading As/Bs
    __bf16* Ts = &As[0][0];  // [2 tiles][64 d][stride 72]
#pragma unroll
    for (int fm = 0; fm < 2; ++fm)
#pragma unroll
      for (int r = 0; r < 4; ++r) {
        const int mo = wm + fm * 16 + quad * 4 + r;  // 0..127 within block
        const int tau = mo >> 6, tt = mo & 63;
        const int p = (tt & 15) * 4 + (tt >> 4);     // inverse of attn's pi
#pragma unroll
        for (int fn = 0; fn < 4; ++fn)
          Ts[tau * 4608 + (fn * 16 + lq) * 72 + p] = (__bf16)acc[fm][fn][r];
      }
    __syncthreads();
    const int b = m0 >> 11, kt0 = (m0 & (kN - 1)) >> 6;
    const int dd = tid >> 2, p0 = (tid & 3) << 4;
#pragma unroll
    for (int tau = 0; tau < 2; ++tau) {
      const __bf16* src = Ts + tau * 4608 + dd * 72 + p0;
      __bf16* dst = vt2 + ((size_t)((b * kH + h) * 32 + kt0 + tau)) * 4096 + tid * 16;
      *(bf16x8*)dst = *(const bf16x8*)src;
      *(bf16x8*)(dst + 8) = *(const bf16x8*)(src + 8);
    }
  } else {
    // ---- Q/K: rms over the 64 cols (4 frags x 16 lq lanes) ----
    const float qs = (n0 < 512) ? (0.125f * LOG2E_F) : 1.0f;
    __bf16* dst0 = (n0 < 512) ? qn : kn;
#pragma unroll
    for (int fm = 0; fm < 2; ++fm)
#pragma unroll
      for (int r = 0; r < 4; ++r) {
        float ss = 0.f;
#pragma unroll
        for (int fn = 0; fn < 4; ++fn) ss += acc[fm][fn][r] * acc[fm][fn][r];
#pragma unroll
        for (int off = 1; off < 16; off <<= 1) ss += __shfl_xor(ss, off, 64);
        const float inv = qs / (sqrtf(ss * (1.f / 64)) + 1e-4f);
        const int m = m0 + wm + fm * 16 + quad * 4 + r;
        const int b = m >> 11, n = m & (kN - 1);
        __bf16* dst = dst0 + ((size_t)(b * kH + h) * kN + n) * kD;
#pragma unroll
        for (int fn = 0; fn < 4; ++fn)
          dst[fn * 16 + lq] = (__bf16)(acc[fm][fn][r] * inv);
      }
  }
}

// ===== fused attention: block = (128-q tile, bh, key-quarter) ==============
// K/V tiles staged to LDS (double-buffered gld16); wave owns 32 q rows.
// Fixed-max softmax (|s| <= 8*SCALE*log2e < 12; bias -12 in MFMA C-init).
// bf16 partials + fp32 row-sums out.
__global__ __launch_bounds__(256, 2) void attn(const __bf16* __restrict__ qn,
                                               const __bf16* __restrict__ kn,
                                               const __bf16* __restrict__ vt2,
                                               __bf16* __restrict__ po,
                                               float* __restrict__ pl) {
  const int qt = blockIdx.x, bh = blockIdx.y, kh = blockIdx.z;
  const int tid = threadIdx.x;
  const int w = tid >> 6, lane = tid & 63, quad = lane >> 4, lq = lane & 15;
  __shared__ __bf16 Ks[2][4096];
  __shared__ __bf16 Vs[2][4096];
  __shared__ __bf16 Ps[4][32 * 72];
  __bf16* myP = Ps[w];

  bf16x8 aq[2][2];
#pragma unroll
  for (int fm = 0; fm < 2; ++fm) {
    const __bf16* Qb = qn + ((size_t)bh * kN + qt * 128 + w * 32 + fm * 16 + lq) * kD;
    aq[fm][0] = *(const bf16x8*)(Qb + quad * 8);
    aq[fm][1] = *(const bf16x8*)(Qb + 32 + quad * 8);
  }

  const f32x4 zero  = {0.f, 0.f, 0.f, 0.f};
  const f32x4 minit = {-12.f, -12.f, -12.f, -12.f};
  f32x4 o[2][4];
  float lr[2][4];
#pragma unroll
  for (int fm = 0; fm < 2; ++fm)
#pragma unroll
    for (int i = 0; i < 4; ++i) { o[fm][i] = zero; lr[fm][i] = 0.f; }

  const __bf16* Kb = kn + ((size_t)bh * kN + kh * 512) * kD;
  const __bf16* Vb = vt2 + (size_t)(bh * 32 + kh * 8) * 4096;

  auto stage = [&](int kt, int buf) {
#pragma unroll
    for (int j = 0; j < 2; ++j) {
      gld16(Kb + (size_t)kt * 4096 + (j * 256 + tid) * 8, &Ks[buf][(j * 256 + tid) * 8]);
      gld16(Vb + (size_t)kt * 4096 + (j * 256 + tid) * 8, &Vs[buf][(j * 256 + tid) * 8]);
    }
  };

  stage(0, 0);
#pragma unroll 2
  for (int kt = 0; kt < 8; ++kt) {
    __syncthreads();
    if (kt < 7) stage(kt + 1, (kt + 1) & 1);
    const __bf16* ks_ = Ks[kt & 1];
    const __bf16* vs_ = Vs[kt & 1];

    bf16x8 kb0[4], kb1[4], vb0[4], vb1[4];
#pragma unroll
    for (int fn = 0; fn < 4; ++fn) {
      const int row = fn * 16 + lq;
      kb0[fn] = *(const bf16x8*)&ks_[row * 64 + quad * 8];
      kb1[fn] = *(const bf16x8*)&ks_[row * 64 + 32 + quad * 8];
      vb0[fn] = *(const bf16x8*)&vs_[row * 64 + quad * 8];
      vb1[fn] = *(const bf16x8*)&vs_[row * 64 + 32 + quad * 8];
    }
    f32x4 s[2][4];
#pragma unroll
    for (int fm = 0; fm < 2; ++fm)
#pragma unroll
      for (int fn = 0; fn < 4; ++fn) {
        f32x4 a = __builtin_amdgcn_mfma_f32_16x16x32_bf16(aq[fm][0], kb0[fn], minit, 0, 0, 0);
        s[fm][fn] = __builtin_amdgcn_mfma_f32_16x16x32_bf16(aq[fm][1], kb1[fn], a, 0, 0, 0);
      }

#pragma unroll
    for (int fm = 0; fm < 2; ++fm)
#pragma unroll
      for (int r = 0; r < 4; ++r) {
        const float p0 = __builtin_amdgcn_exp2f(s[fm][0][r]);
        const float p1 = __builtin_amdgcn_exp2f(s[fm][1][r]);
        const float p2 = __builtin_amdgcn_exp2f(s[fm][2][r]);
        const float p3 = __builtin_amdgcn_exp2f(s[fm][3][r]);
        lr[fm][r] += (p0 + p1) + (p2 + p3);
        bf16x4 pk = {(__bf16)p0, (__bf16)p1, (__bf16)p2, (__bf16)p3};
        *(bf16x4*)&myP[(fm * 16 + quad * 4 + r) * 72 + lq * 4] = pk;
      }

#pragma unroll
    for (int fm = 0; fm < 2; ++fm) {
      bf16x8 ap0 = *(const bf16x8*)&myP[(fm * 16 + lq) * 72 + quad * 8];
      bf16x8 ap1 = *(const bf16x8*)&myP[(fm * 16 + lq) * 72 + 32 + quad * 8];
#pragma unroll
      for (int fn = 0; fn < 4; ++fn) {
        o[fm][fn] = __builtin_amdgcn_mfma_f32_16x16x32_bf16(ap0, vb0[fn], o[fm][fn], 0, 0, 0);
        o[fm][fn] = __builtin_amdgcn_mfma_f32_16x16x32_bf16(ap1, vb1[fn], o[fm][fn], 0, 0, 0);
      }
    }
  }

  const int b = bh >> 3, h = bh & 7;
#pragma unroll
  for (int fm = 0; fm < 2; ++fm) {
    const int qrow0 = qt * 128 + w * 32 + fm * 16 + quad * 4;
#pragma unroll
    for (int r = 0; r < 4; ++r) {
      float sum = lr[fm][r];
#pragma unroll
      for (int off = 1; off < 16; off <<= 1) sum += __shfl_xor(sum, off, 64);
      if (lq == 0) pl[(size_t)kh * 32768 + bh * kN + qrow0 + r] = sum;
      const size_t ob = ((size_t)kh * kTok + b * kN + qrow0 + r) * kDim + h * 64;
#pragma unroll
      for (int fn = 0; fn < 4; ++fn) po[ob + fn * 16 + lq] = (__bf16)o[fm][fn][r];
    }
  }
}

// ===== combine quarters: ao = (sum o_kh)/(sum l_kh), bf16 ==================
__global__ __launch_bounds__(256) void combine(const __bf16* __restrict__ po,
                                               const float* __restrict__ pl,
                                               __bf16* __restrict__ ao) {
  const size_t i = ((size_t)blockIdx.x * 256 + threadIdx.x) * 4;
  const int tok = (int)(i >> 9), dk = (int)(i & 511);
  const int h = dk >> 6, b = tok >> 11, qrow = tok & (kN - 1);
  const int idx = (b * kH + h) * kN + qrow;
  float l = 0.f;
#pragma unroll
  for (int kh = 0; kh < kKH; ++kh) l += pl[kh * 32768 + idx];
  const float inv = 1.f / l;
  float s0 = 0.f, s1 = 0.f, s2 = 0.f, s3 = 0.f;
#pragma unroll
  for (int kh = 0; kh < kKH; ++kh) {
    bf16x4 a = *(const bf16x4*)(po + (size_t)kh * kTok * kDim + i);
    s0 += (float)a[0]; s1 += (float)a[1]; s2 += (float)a[2]; s3 += (float)a[3];
  }
  bf16x4 t = {(__bf16)(s0 * inv), (__bf16)(s1 * inv),
              (__bf16)(s2 * inv), (__bf16)(s3 * inv)};
  *(bf16x4*)(ao + i) = t;
}

// ===== out-proj GEMM: C[M,512] = A*B^T, 64x64 tile, grid 512 (2 blk/CU) ====
__global__ __launch_bounds__(256, 2) void gemm64(const __bf16* __restrict__ A,
                                                 const __bf16* __restrict__ B,
                                                 float* __restrict__ C,
                                                 int N, int K) {
  const int tid = threadIdx.x;
  const int w = tid >> 6, lane = tid & 63, quad = lane >> 4, lq = lane & 15;
  const int m0 = blockIdx.y * 64;
  const int n0 = blockIdx.x * 64;
  const int wm = (w >> 1) * 32, wn = (w & 1) * 32;
  __shared__ __bf16 As[2][4096];
  __shared__ __bf16 Bs[2][4096];

  const f32x4 zero = {0.f, 0.f, 0.f, 0.f};
  f32x4 acc00 = zero, acc01 = zero, acc10 = zero, acc11 = zero;

  const int sr = tid >> 3, sc = (tid & 7) << 3;
  auto stage = [&](int k0, int buf) {
#pragma unroll
    for (int j = 0; j < 2; ++j) {
      gld16(A + (size_t)(m0 + j * 32 + sr) * K + k0 + sc,
            &As[buf][(j * 32 + sr) * 64 + sc]);
      gld16(B + (size_t)(n0 + j * 32 + sr) * K + k0 + sc,
            &Bs[buf][(j * 32 + sr) * 64 + sc]);
    }
  };

  stage(0, 0);
  const int iters = K >> 6;
  for (int i = 0; i < iters; ++i) {
    __syncthreads();
    if (i + 1 < iters) stage((i + 1) << 6, (i + 1) & 1);
    const __bf16* as = As[i & 1];
    const __bf16* bs = Bs[i & 1];
#pragma unroll
    for (int ks = 0; ks < 2; ++ks) {
      bf16x8 a0 = *(const bf16x8*)&as[(wm +      lq) * 64 + ks * 32 + quad * 8];
      bf16x8 a1 = *(const bf16x8*)&as[(wm + 16 + lq) * 64 + ks * 32 + quad * 8];
      bf16x8 b0 = *(const bf16x8*)&bs[(wn +      lq) * 64 + ks * 32 + quad * 8];
      bf16x8 b1 = *(const bf16x8*)&bs[(wn + 16 + lq) * 64 + ks * 32 + quad * 8];
      acc00 = __builtin_amdgcn_mfma_f32_16x16x32_bf16(a0, b0, acc00, 0, 0, 0);
      acc01 = __builtin_amdgcn_mfma_f32_16x16x32_bf16(a0, b1, acc01, 0, 0, 0);
      acc10 = __builtin_amdgcn_mfma_f32_16x16x32_bf16(a1, b0, acc10, 0, 0, 0);
      acc11 = __builtin_amdgcn_mfma_f32_16x16x32_bf16(a1, b1, acc11, 0, 0, 0);
    }
  }
  const f32x4 av[2][2] = {{acc00, acc01}, {acc10, acc11}};
#pragma unroll
  for (int fm = 0; fm < 2; ++fm)
#pragma unroll
    for (int fn = 0; fn < 2; ++fn)
#pragma unroll
      for (int r = 0; r < 4; ++r)
        C[(size_t)(m0 + wm + fm * 16 + quad * 4 + r) * N + (n0 + wn + fn * 16 + lq)] =
            av[fm][fn][r];
}

// ===========================================================================
extern "C" void kernel_launch(void* const* d_in, const int* in_sizes, int n_in,
                              void* d_out, int out_size, void* d_ws, size_t ws_size,
                              hipStream_t stream) {
  const float* x    = (const float*)d_in[0];
  const float* Wq   = (const float*)d_in[1];
  const float* Wkv  = (const float*)d_in[2];
  const float* Wout = (const float*)d_in[3];
  float* out = (float*)d_out;
  char* ws = (char*)d_ws;

  __bf16* xb    = (__bf16*)(ws);                       //  0..4M   [4096,512]
  __bf16* wqkvb = (__bf16*)(ws + (size_t)(4 << 20));   //  4..5.5M [1536,512]
  __bf16* wob   = (__bf16*)(ws + (size_t)(6 << 20));   //  6..6.5M [512,512]
  __bf16* qn    = (__bf16*)(ws + (size_t)(7 << 20));   //  7..11M  [bh][n][d]
  __bf16* kn    = (__bf16*)(ws + (size_t)(11 << 20));  // 11..15M  [bh][n][d]
  __bf16* vt2   = (__bf16*)(ws + (size_t)(15 << 20));  // 15..19M  tiled V^T
  __bf16* po    = (__bf16*)(ws + (size_t)(19 << 20));  // 19..35M  partials x4
  float*  pl    = (float*)(ws + (size_t)(35 << 20));   // 35..35.5M
  __bf16* ao    = (__bf16*)(ws + (size_t)(36 << 20));  // 36..40M  [tok][dim]

  cvt_all<<<1536, 256, 0, stream>>>(x, Wq, Wkv, Wout, xb, wqkvb, wob);
  gemm_qkv<<<dim3(kNQKV / 64, kTok / 128), 256, 0, stream>>>(xb, wqkvb, qn, kn, vt2);
  attn<<<dim3(kN / 128, kB * kH, kKH), 256, 0, stream>>>(qn, kn, vt2, po, pl);
  combine<<<kTok * kDim / 1024, 256, 0, stream>>>(po, pl, ao);
  gemm64<<<dim3(kDim / 64, kTok / 64), 256, 0, stream>>>(ao, wob, out, kDim, kDim);
}

// Round 6
// 118.301 us; speedup vs baseline: 2.0966x; 1.0967x over previous
//
#include <hip/hip_runtime.h>

typedef __bf16 bf16x8 __attribute__((ext_vector_type(8)));
typedef __bf16 bf16x4 __attribute__((ext_vector_type(4)));
typedef float  f32x4  __attribute__((ext_vector_type(4)));

#define LOG2E_F 1.44269504088896340736f

static constexpr int kB = 2, kN = 2048, kH = 8, kD = 64, kDim = 512;
static constexpr int kTok = kB * kN;   // 4096
static constexpr int kNQKV = 1536;     // fused Wq(512)+Wkv(1024) rows
static constexpr int kKH = 3;          // attention split-K: 11/11/10 kt tiles

__device__ __forceinline__ void gld16(const void* g, void* l) {
  __builtin_amdgcn_global_load_lds(
      (const __attribute__((address_space(1))) void*)g,
      (__attribute__((address_space(3))) void*)l, 16, 0, 0);
}

// XOR-swizzled LDS tiles (rows of 64 bf16 = 8 chunks of 16B):
// LDS chunk c of row r holds GLOBAL chunk c^(r&7). Staged via per-lane source
// permutation (gld16 dest stays lane-linear); readers XOR their chunk index
// with (row&7). Spreads quad-group b128 reads over all 32 banks (the naive
// layout parks each quad on a 4-bank group -> 2x port inflation).

// ===== fp32 -> bf16 linear converts: x | Wq | Wkv (fused) | Wout ===========
__global__ __launch_bounds__(256) void cvt_all(const float* __restrict__ x,
                                               const float* __restrict__ wq,
                                               const float* __restrict__ wkv,
                                               const float* __restrict__ wo,
                                               __bf16* __restrict__ xb,
                                               __bf16* __restrict__ wqkvb,
                                               __bf16* __restrict__ wob) {
  size_t i = ((size_t)blockIdx.x * 256 + threadIdx.x) * 8;
  const float* s; __bf16* d; size_t off;
  if (i < 2097152)      { s = x;   d = xb;              off = i; }
  else if (i < 2359296) { s = wq;  d = wqkvb;           off = i - 2097152; }
  else if (i < 2883584) { s = wkv; d = wqkvb + 262144;  off = i - 2359296; }
  else                  { s = wo;  d = wob;             off = i - 2883584; }
  float4 u = *(const float4*)(s + off);
  float4 v = *(const float4*)(s + off + 4);
  bf16x8 t;
  t[0] = (__bf16)u.x; t[1] = (__bf16)u.y; t[2] = (__bf16)u.z; t[3] = (__bf16)u.w;
  t[4] = (__bf16)v.x; t[5] = (__bf16)v.y; t[6] = (__bf16)v.z; t[7] = (__bf16)v.w;
  *(bf16x8*)(d + off) = t;
}

// ===== QKV GEMM with fused norm/transpose epilogue =========================
__global__ __launch_bounds__(256, 3) void gemm_qkv(const __bf16* __restrict__ A,
                                                   const __bf16* __restrict__ B,
                                                   __bf16* __restrict__ qn,
                                                   __bf16* __restrict__ kn,
                                                   __bf16* __restrict__ vt2) {
  const int K = kDim;
  const int tid = threadIdx.x;
  const int w = tid >> 6, lane = tid & 63, quad = lane >> 4, lq = lane & 15;
  const int m0 = blockIdx.y * 128;
  const int n0 = blockIdx.x * 64;
  const int wm = w * 32;
  __shared__ __bf16 As[2][128 * 64];
  __shared__ __bf16 Bs[2][64 * 64];

  const f32x4 zero = {0.f, 0.f, 0.f, 0.f};
  f32x4 acc[2][4];
#pragma unroll
  for (int fm = 0; fm < 2; ++fm)
#pragma unroll
    for (int fn = 0; fn < 4; ++fn) acc[fm][fn] = zero;

  const int sr = tid >> 3, ch = tid & 7;
  auto stage = [&](int k0, int buf) {
#pragma unroll
    for (int j = 0; j < 4; ++j) {
      const int row = j * 32 + sr;
      gld16(A + (size_t)(m0 + row) * K + k0 + ((ch ^ (row & 7)) << 3),
            &As[buf][row * 64 + ch * 8]);
    }
#pragma unroll
    for (int j = 0; j < 2; ++j) {
      const int row = j * 32 + sr;
      gld16(B + (size_t)(n0 + row) * K + k0 + ((ch ^ (row & 7)) << 3),
            &Bs[buf][row * 64 + ch * 8]);
    }
  };
  // swizzled chunk offsets for frag reads (row&7 == lq&7 for all our rows)
  const int sw0 = ((quad ^ (lq & 7)) << 3);        // ks=0
  const int sw1 = (((4 | quad) ^ (lq & 7)) << 3);  // ks=1

  stage(0, 0);
  for (int i = 0; i < 8; ++i) {
    __syncthreads();
    if (i + 1 < 8) stage((i + 1) << 6, (i + 1) & 1);
    const __bf16* as = As[i & 1];
    const __bf16* bs = Bs[i & 1];
#pragma unroll
    for (int ks = 0; ks < 2; ++ks) {
      const int sw = ks ? sw1 : sw0;
      bf16x8 a[2], b[4];
#pragma unroll
      for (int fm = 0; fm < 2; ++fm)
        a[fm] = *(const bf16x8*)&as[(wm + fm * 16 + lq) * 64 + sw];
#pragma unroll
      for (int fn = 0; fn < 4; ++fn)
        b[fn] = *(const bf16x8*)&bs[(fn * 16 + lq) * 64 + sw];
#pragma unroll
      for (int fm = 0; fm < 2; ++fm)
#pragma unroll
        for (int fn = 0; fn < 4; ++fn)
          acc[fm][fn] =
              __builtin_amdgcn_mfma_f32_16x16x32_bf16(a[fm], b[fn], acc[fm][fn], 0, 0, 0);
    }
  }

  const int h = (n0 >> 6) & 7;
  if (n0 >= 1024) {
    // ---- V: transpose via LDS (reuse As), then coalesced 16B stores ----
    __syncthreads();
    __bf16* Ts = &As[0][0];  // [2 tiles][64 d][stride 72]
#pragma unroll
    for (int fm = 0; fm < 2; ++fm)
#pragma unroll
      for (int r = 0; r < 4; ++r) {
        const int mo = wm + fm * 16 + quad * 4 + r;
        const int tau = mo >> 6, tt = mo & 63;
        const int p = (tt & 15) * 4 + (tt >> 4);  // inverse of attn's pi
#pragma unroll
        for (int fn = 0; fn < 4; ++fn)
          Ts[tau * 4608 + (fn * 16 + lq) * 72 + p] = (__bf16)acc[fm][fn][r];
      }
    __syncthreads();
    const int b = m0 >> 11, kt0 = (m0 & (kN - 1)) >> 6;
    const int dd = tid >> 2, p0 = (tid & 3) << 4;
#pragma unroll
    for (int tau = 0; tau < 2; ++tau) {
      const __bf16* src = Ts + tau * 4608 + dd * 72 + p0;
      __bf16* dst = vt2 + ((size_t)((b * kH + h) * 32 + kt0 + tau)) * 4096 + tid * 16;
      *(bf16x8*)dst = *(const bf16x8*)src;
      *(bf16x8*)(dst + 8) = *(const bf16x8*)(src + 8);
    }
  } else {
    // ---- Q/K: rms over the 64 cols ----
    const float qs = (n0 < 512) ? (0.125f * LOG2E_F) : 1.0f;
    __bf16* dst0 = (n0 < 512) ? qn : kn;
#pragma unroll
    for (int fm = 0; fm < 2; ++fm)
#pragma unroll
      for (int r = 0; r < 4; ++r) {
        float ss = 0.f;
#pragma unroll
        for (int fn = 0; fn < 4; ++fn) ss += acc[fm][fn][r] * acc[fm][fn][r];
#pragma unroll
        for (int off = 1; off < 16; off <<= 1) ss += __shfl_xor(ss, off, 64);
        const float inv = qs / (sqrtf(ss * (1.f / 64)) + 1e-4f);
        const int m = m0 + wm + fm * 16 + quad * 4 + r;
        const int b = m >> 11, n = m & (kN - 1);
        __bf16* dst = dst0 + ((size_t)(b * kH + h) * kN + n) * kD;
#pragma unroll
        for (int fn = 0; fn < 4; ++fn)
          dst[fn * 16 + lq] = (__bf16)(acc[fm][fn][r] * inv);
      }
  }
}

// ===== fused attention: block = (128-q tile, bh, key-third) ================
// Swizzled K/V LDS staging (conflict-free b128 frag reads); wave owns 32 q.
// Fixed-max softmax (|s| <= 11.54 < 12; bias -12 in MFMA C-init).
__global__ __launch_bounds__(256, 3) void attn(const __bf16* __restrict__ qn,
                                               const __bf16* __restrict__ kn,
                                               const __bf16* __restrict__ vt2,
                                               __bf16* __restrict__ po,
                                               float* __restrict__ pl) {
  const int qt = blockIdx.x, bh = blockIdx.y, kh = blockIdx.z;
  const int kt0 = kh * 11;
  const int cnt = (kh == 2) ? 10 : 11;
  const int tid = threadIdx.x;
  const int w = tid >> 6, lane = tid & 63, quad = lane >> 4, lq = lane & 15;
  __shared__ __bf16 Ks[2][4096];
  __shared__ __bf16 Vs[2][4096];
  __shared__ __bf16 Ps[4][32 * 72];
  __bf16* myP = Ps[w];

  bf16x8 aq[2][2];
#pragma unroll
  for (int fm = 0; fm < 2; ++fm) {
    const __bf16* Qb = qn + ((size_t)bh * kN + qt * 128 + w * 32 + fm * 16 + lq) * kD;
    aq[fm][0] = *(const bf16x8*)(Qb + quad * 8);
    aq[fm][1] = *(const bf16x8*)(Qb + 32 + quad * 8);
  }

  const f32x4 zero  = {0.f, 0.f, 0.f, 0.f};
  const f32x4 minit = {-12.f, -12.f, -12.f, -12.f};
  f32x4 o[2][4];
  float lr[2][4];
#pragma unroll
  for (int fm = 0; fm < 2; ++fm)
#pragma unroll
    for (int i = 0; i < 4; ++i) { o[fm][i] = zero; lr[fm][i] = 0.f; }

  const __bf16* Kb = kn + (size_t)bh * kN * kD;   // tile ktg at +ktg*4096
  const __bf16* Vb = vt2 + (size_t)bh * 32 * 4096;

  auto stage = [&](int ktg, int buf) {
#pragma unroll
    for (int j = 0; j < 2; ++j) {
      const int s = j * 256 + tid;
      const int row = s >> 3, ch = s & 7;
      const int src = row * 64 + ((ch ^ (row & 7)) << 3);
      gld16(Kb + (size_t)ktg * 4096 + src, &Ks[buf][s * 8]);
      gld16(Vb + (size_t)ktg * 4096 + src, &Vs[buf][s * 8]);
    }
  };
  const int sw0 = ((quad ^ (lq & 7)) << 3);
  const int sw1 = (((4 | quad) ^ (lq & 7)) << 3);

  stage(kt0, 0);
  for (int kt = 0; kt < cnt; ++kt) {
    __syncthreads();
    if (kt + 1 < cnt) stage(kt0 + kt + 1, (kt + 1) & 1);
    const __bf16* ks_ = Ks[kt & 1];
    const __bf16* vs_ = Vs[kt & 1];

    bf16x8 kb0[4], kb1[4], vb0[4], vb1[4];
#pragma unroll
    for (int fn = 0; fn < 4; ++fn) {
      const int rb = (fn * 16 + lq) * 64;
      kb0[fn] = *(const bf16x8*)&ks_[rb + sw0];
      kb1[fn] = *(const bf16x8*)&ks_[rb + sw1];
      vb0[fn] = *(const bf16x8*)&vs_[rb + sw0];
      vb1[fn] = *(const bf16x8*)&vs_[rb + sw1];
    }
    f32x4 s[2][4];
#pragma unroll
    for (int fm = 0; fm < 2; ++fm)
#pragma unroll
      for (int fn = 0; fn < 4; ++fn) {
        f32x4 a = __builtin_amdgcn_mfma_f32_16x16x32_bf16(aq[fm][0], kb0[fn], minit, 0, 0, 0);
        s[fm][fn] = __builtin_amdgcn_mfma_f32_16x16x32_bf16(aq[fm][1], kb1[fn], a, 0, 0, 0);
      }

#pragma unroll
    for (int fm = 0; fm < 2; ++fm)
#pragma unroll
      for (int r = 0; r < 4; ++r) {
        const float p0 = __builtin_amdgcn_exp2f(s[fm][0][r]);
        const float p1 = __builtin_amdgcn_exp2f(s[fm][1][r]);
        const float p2 = __builtin_amdgcn_exp2f(s[fm][2][r]);
        const float p3 = __builtin_amdgcn_exp2f(s[fm][3][r]);
        lr[fm][r] += (p0 + p1) + (p2 + p3);
        bf16x4 pk = {(__bf16)p0, (__bf16)p1, (__bf16)p2, (__bf16)p3};
        *(bf16x4*)&myP[(fm * 16 + quad * 4 + r) * 72 + lq * 4] = pk;
      }

#pragma unroll
    for (int fm = 0; fm < 2; ++fm) {
      bf16x8 ap0 = *(const bf16x8*)&myP[(fm * 16 + lq) * 72 + quad * 8];
      bf16x8 ap1 = *(const bf16x8*)&myP[(fm * 16 + lq) * 72 + 32 + quad * 8];
#pragma unroll
      for (int fn = 0; fn < 4; ++fn) {
        o[fm][fn] = __builtin_amdgcn_mfma_f32_16x16x32_bf16(ap0, vb0[fn], o[fm][fn], 0, 0, 0);
        o[fm][fn] = __builtin_amdgcn_mfma_f32_16x16x32_bf16(ap1, vb1[fn], o[fm][fn], 0, 0, 0);
      }
    }
  }

  const int b = bh >> 3, h = bh & 7;
#pragma unroll
  for (int fm = 0; fm < 2; ++fm) {
    const int qrow0 = qt * 128 + w * 32 + fm * 16 + quad * 4;
#pragma unroll
    for (int r = 0; r < 4; ++r) {
      float sum = lr[fm][r];
#pragma unroll
      for (int off = 1; off < 16; off <<= 1) sum += __shfl_xor(sum, off, 64);
      if (lq == 0) pl[(size_t)kh * 32768 + bh * kN + qrow0 + r] = sum;
      const size_t ob = ((size_t)kh * kTok + b * kN + qrow0 + r) * kDim + h * 64;
#pragma unroll
      for (int fn = 0; fn < 4; ++fn) po[ob + fn * 16 + lq] = (__bf16)o[fm][fn][r];
    }
  }
}

// ===== combine thirds: ao = (sum o_kh)/(sum l_kh), bf16 ====================
__global__ __launch_bounds__(256) void combine(const __bf16* __restrict__ po,
                                               const float* __restrict__ pl,
                                               __bf16* __restrict__ ao) {
  const size_t i = ((size_t)blockIdx.x * 256 + threadIdx.x) * 4;
  const int tok = (int)(i >> 9), dk = (int)(i & 511);
  const int h = dk >> 6, b = tok >> 11, qrow = tok & (kN - 1);
  const int idx = (b * kH + h) * kN + qrow;
  float l = 0.f;
#pragma unroll
  for (int kh = 0; kh < kKH; ++kh) l += pl[kh * 32768 + idx];
  const float inv = 1.f / l;
  float s0 = 0.f, s1 = 0.f, s2 = 0.f, s3 = 0.f;
#pragma unroll
  for (int kh = 0; kh < kKH; ++kh) {
    bf16x4 a = *(const bf16x4*)(po + (size_t)kh * kTok * kDim + i);
    s0 += (float)a[0]; s1 += (float)a[1]; s2 += (float)a[2]; s3 += (float)a[3];
  }
  bf16x4 t = {(__bf16)(s0 * inv), (__bf16)(s1 * inv),
              (__bf16)(s2 * inv), (__bf16)(s3 * inv)};
  *(bf16x4*)(ao + i) = t;
}

// ===== out-proj GEMM: C[M,512] = A*B^T, 64x64 tile =========================
__global__ __launch_bounds__(256, 2) void gemm64(const __bf16* __restrict__ A,
                                                 const __bf16* __restrict__ B,
                                                 float* __restrict__ C,
                                                 int N, int K) {
  const int tid = threadIdx.x;
  const int w = tid >> 6, lane = tid & 63, quad = lane >> 4, lq = lane & 15;
  const int m0 = blockIdx.y * 64;
  const int n0 = blockIdx.x * 64;
  const int wm = (w >> 1) * 32, wn = (w & 1) * 32;
  __shared__ __bf16 As[2][4096];
  __shared__ __bf16 Bs[2][4096];

  const f32x4 zero = {0.f, 0.f, 0.f, 0.f};
  f32x4 acc00 = zero, acc01 = zero, acc10 = zero, acc11 = zero;

  const int sr = tid >> 3, ch = tid & 7;
  auto stage = [&](int k0, int buf) {
#pragma unroll
    for (int j = 0; j < 2; ++j) {
      const int row = j * 32 + sr;
      const int src = k0 + ((ch ^ (row & 7)) << 3);
      gld16(A + (size_t)(m0 + row) * K + src, &As[buf][row * 64 + ch * 8]);
      gld16(B + (size_t)(n0 + row) * K + src, &Bs[buf][row * 64 + ch * 8]);
    }
  };
  const int sw0 = ((quad ^ (lq & 7)) << 3);
  const int sw1 = (((4 | quad) ^ (lq & 7)) << 3);

  stage(0, 0);
  const int iters = K >> 6;
  for (int i = 0; i < iters; ++i) {
    __syncthreads();
    if (i + 1 < iters) stage((i + 1) << 6, (i + 1) & 1);
    const __bf16* as = As[i & 1];
    const __bf16* bs = Bs[i & 1];
#pragma unroll
    for (int ks = 0; ks < 2; ++ks) {
      const int sw = ks ? sw1 : sw0;
      bf16x8 a0 = *(const bf16x8*)&as[(wm +      lq) * 64 + sw];
      bf16x8 a1 = *(const bf16x8*)&as[(wm + 16 + lq) * 64 + sw];
      bf16x8 b0 = *(const bf16x8*)&bs[(wn +      lq) * 64 + sw];
      bf16x8 b1 = *(const bf16x8*)&bs[(wn + 16 + lq) * 64 + sw];
      acc00 = __builtin_amdgcn_mfma_f32_16x16x32_bf16(a0, b0, acc00, 0, 0, 0);
      acc01 = __builtin_amdgcn_mfma_f32_16x16x32_bf16(a0, b1, acc01, 0, 0, 0);
      acc10 = __builtin_amdgcn_mfma_f32_16x16x32_bf16(a1, b0, acc10, 0, 0, 0);
      acc11 = __builtin_amdgcn_mfma_f32_16x16x32_bf16(a1, b1, acc11, 0, 0, 0);
    }
  }
  const f32x4 av[2][2] = {{acc00, acc01}, {acc10, acc11}};
#pragma unroll
  for (int fm = 0; fm < 2; ++fm)
#pragma unroll
    for (int fn = 0; fn < 2; ++fn)
#pragma unroll
      for (int r = 0; r < 4; ++r)
        C[(size_t)(m0 + wm + fm * 16 + quad * 4 + r) * N + (n0 + wn + fn * 16 + lq)] =
            av[fm][fn][r];
}

// ===========================================================================
extern "C" void kernel_launch(void* const* d_in, const int* in_sizes, int n_in,
                              void* d_out, int out_size, void* d_ws, size_t ws_size,
                              hipStream_t stream) {
  const float* x    = (const float*)d_in[0];
  const float* Wq   = (const float*)d_in[1];
  const float* Wkv  = (const float*)d_in[2];
  const float* Wout = (const float*)d_in[3];
  float* out = (float*)d_out;
  char* ws = (char*)d_ws;

  __bf16* xb    = (__bf16*)(ws);                       //  0..4M   [4096,512]
  __bf16* wqkvb = (__bf16*)(ws + (size_t)(4 << 20));   //  4..5.5M [1536,512]
  __bf16* wob   = (__bf16*)(ws + (size_t)(6 << 20));   //  6..6.5M [512,512]
  __bf16* qn    = (__bf16*)(ws + (size_t)(7 << 20));   //  7..11M  [bh][n][d]
  __bf16* kn    = (__bf16*)(ws + (size_t)(11 << 20));  // 11..15M  [bh][n][d]
  __bf16* vt2   = (__bf16*)(ws + (size_t)(15 << 20));  // 15..19M  tiled V^T
  __bf16* po    = (__bf16*)(ws + (size_t)(19 << 20));  // 19..31M  partials x3
  float*  pl    = (float*)(ws + (size_t)(32 << 20));   // 32..32.4M
  __bf16* ao    = (__bf16*)(ws + (size_t)(33 << 20));  // 33..37M  [tok][dim]

  cvt_all<<<1536, 256, 0, stream>>>(x, Wq, Wkv, Wout, xb, wqkvb, wob);
  gemm_qkv<<<dim3(kNQKV / 64, kTok / 128), 256, 0, stream>>>(xb, wqkvb, qn, kn, vt2);
  attn<<<dim3(kN / 128, kB * kH, kKH), 256, 0, stream>>>(qn, kn, vt2, po, pl);
  combine<<<kTok * kDim / 1024, 256, 0, stream>>>(po, pl, ao);
  gemm64<<<dim3(kDim / 64, kTok / 64), 256, 0, stream>>>(ao, wob, out, kDim, kDim);
}